// Round 6
// baseline (1353.753 us; speedup 1.0000x reference)
//
#include <hip/hip_runtime.h>

typedef _Float16 f16;
typedef _Float16 f16x4 __attribute__((ext_vector_type(4)));
typedef _Float16 f16x8 __attribute__((ext_vector_type(8)));
typedef float f32x4 __attribute__((ext_vector_type(4)));
typedef float f32x16 __attribute__((ext_vector_type(16)));

#define MFMA32(A, B, C) __builtin_amdgcn_mfma_f32_32x32x16_f16(A, B, C, 0, 0, 0)

constexpr int Bb = 4, Hh = 8, Ll = 2048, Dk = 64, Dm = 512, BH = 32;

// element counts per (tensor,hilo) array
constexpr size_t NWF = (size_t)16 * 128 * 64 * 8;      // W frag: [ob16][k16:128][lane][8]
constexpr size_t NAF = (size_t)Bb * 64 * 128 * 64 * 8; // A frag: [b][tb64][k16:128][lane][8]
constexpr size_t NFF = (size_t)BH * 64 * 4 * 64 * 8;   // Qc/Kc frag: [bh][lb64][d16:4][lane][8]
constexpr size_t NVF = (size_t)BH * 2 * 128 * 64 * 8;  // V frag: [bh][db2][l16:128][lane][8]

constexpr size_t OFF_WF = 256;
constexpr size_t OFF_AF = OFF_WF + 4 * NWF * sizeof(f16);
constexpr size_t OFF_FF = OFF_AF + 4 * NAF * sizeof(f16);
constexpr size_t OFF_VF = OFF_FF + 4 * NFF * sizeof(f16);

// scores computed in base-2: fold log2(e)/sqrt(64) into Qc (exact softmax identity)
#define QSCALE 0.1803368801111204f

// ---------------- P1: mask + split conv weights into frag order ----------------
__global__ void kprep_w(const float* __restrict__ convq, const float* __restrict__ convk,
                        const float* __restrict__ w, int* __restrict__ flag,
                        f16* __restrict__ wfhq, f16* __restrict__ wflq,
                        f16* __restrict__ wfhk, f16* __restrict__ wflk) {
    const int len = (4.f * w[1] > 2.f * w[0]) ? 4 : 2;   // argmax([2w0,4w1]) -> FILTER_LENGTHS[ind]
    if (blockIdx.x == 0 && blockIdx.y == 0 && threadIdx.x == 0) *flag = len;
    int tid = blockIdx.x * 256 + threadIdx.x;            // 0..262143 = c*512+o
    int o = tid & 511;
    const float* conv = blockIdx.y ? convk : convq;
    f16* dh = blockIdx.y ? wfhk : wfhq;
    f16* dl = blockIdx.y ? wflk : wflq;
    const float4 v = *(const float4*)(conv + (size_t)tid * 4);  // conv[c][o][0..3]
    float vv[4] = {v.x, v.y, v.z, v.w};
    int c = tid >> 9, ob = o >> 5;
#pragma unroll
    for (int f = 0; f < 4; ++f) {
        float x = (f < len) ? vv[f] : 0.f;
        f16 hi = (f16)x;
        f16 lo = (f16)(x - (float)hi);
        int k = (f << 9) + c;
        size_t idx = (((size_t)ob * 128 + (k >> 4)) * 64 + ((k >> 3) & 1) * 32 + (o & 31)) * 8 + (k & 7);
        dh[idx] = hi; dl[idx] = lo;
    }
}

// ---------------- P2: conv A operand, frag order, f-shift baked in ----------------
__global__ void kprep_a(const float* __restrict__ Q, const float* __restrict__ K,
                        const int* __restrict__ flag,
                        f16* __restrict__ afhq, f16* __restrict__ aflq,
                        f16* __restrict__ afhk, f16* __restrict__ aflk) {
    __shared__ float tile[64][36];
    int tensor = blockIdx.z, b = blockIdx.y;
    int tb = blockIdx.x >> 5, k16g = blockIdx.x & 31;
    int f = k16g >> 3;                       // constant over the block's 64 k's
    if (f >= *flag) return;                  // masked f: weights are zero and kconv never reads
    int c0 = (k16g * 64) & 511;
    const float* S = (tensor ? K : Q) + (size_t)b * Dm * Ll;  // flat b x 512 x 2048 view
    int tid = threadIdx.x;
    int t0 = tb * 32;
#pragma unroll
    for (int i = 0; i < 9; ++i) {
        int e = i * 256 + tid;               // 0..2303
        int row = e / 36, col = e - row * 36;
        int t = t0 - 2 + col;
        tile[row][col] = (t >= 0 && t < Ll) ? S[(size_t)(c0 + row) * Ll + t] : 0.f;
    }
    __syncthreads();
    int sub = tid >> 6, lane = tid & 63;
    int k16 = k16g * 4 + sub;
    int khalf = lane >> 5, lane31 = lane & 31;
    f16x8 hv, lv;
#pragma unroll
    for (int j = 0; j < 8; ++j) {
        int cl = sub * 16 + khalf * 8 + j;
        float x = tile[cl][lane31 + f];
        f16 hi = (f16)x;
        hv[j] = hi; lv[j] = (f16)(x - (float)hi);
    }
    f16* dh = tensor ? afhk : afhq;
    f16* dl = tensor ? aflk : aflq;
    size_t idx = ((((size_t)b * 64 + tb) * 128 + k16) * 64 + lane) * 8;
    *(f16x8*)(dh + idx) = hv;
    *(f16x8*)(dl + idx) = lv;
}

// ---------------- P3: V -> frag order for PV B-operand ----------------
__global__ void kprep_v(const float* __restrict__ V, f16* __restrict__ vf) {
    int bh = blockIdx.y, l0 = blockIdx.x * 128;
    int tid = threadIdx.x;
    const float* src = V + (size_t)bh * Ll * Dk;
#pragma unroll
    for (int s = 0; s < 4; ++s) {
        int g = s * 4 + (tid >> 6);
        int lane = tid & 63;
        int l16s = g >> 1, db = g & 1;
        int khalf = lane >> 5, lane31 = lane & 31;
        int d = db * 32 + lane31;
        f16x8 out;
#pragma unroll
        for (int j = 0; j < 8; ++j) {
            int l = l0 + l16s * 16 + khalf * 8 + j;
            out[j] = (f16)src[(size_t)l * Dk + d];
        }
        size_t idx = ((((size_t)bh * 2 + db) * 128 + (l0 >> 4) + l16s) * 64 + lane) * 8;
        *(f16x8*)(vf + idx) = out;
    }
}

// ---------------- C: conv GEMM, 1024 blocks, ping-pong pipelined frag loads ----------------
// R6: swizzle reverted to R4 (R5's tensor/oTile-per-XCD map decorrelated kconv's ff
// writes from kattn's readers -> kattn FETCH 28->78MB, net regression).
__global__ __launch_bounds__(256, 4) void kconv(
    const float* __restrict__ Q, const float* __restrict__ K, const int* __restrict__ flag,
    const f16* __restrict__ afhq, const f16* __restrict__ aflq,
    const f16* __restrict__ afhk, const f16* __restrict__ aflk,
    const f16* __restrict__ wfhq, const f16* __restrict__ wflq,
    const f16* __restrict__ wfhk, const f16* __restrict__ wflk,
    f16* __restrict__ ffhq, f16* __restrict__ fflq,
    f16* __restrict__ ffhk, f16* __restrict__ fflk) {
    int id = blockIdx.x;                        // XCD swizzle: 4 oTile-siblings share id&7
    int xcd = id & 7, oTile = (id >> 3) & 3, gidx = id >> 5;
    int g = gidx * 8 + xcd;
    int tt = g & 31, b = (g >> 5) & 3, tensor = (g >> 7) & 1;
    int wave = threadIdx.x >> 6, lane = threadIdx.x & 63;
    int wn = wave & 1, wm = wave >> 1;
    int lane31 = lane & 31, khalf = lane >> 5;
    const f16* ah = (tensor ? afhk : afhq) + ((size_t)(b * 64 + tt * 2 + wm) * 128) * 512;
    const f16* al = (tensor ? aflk : aflq) + ((size_t)(b * 64 + tt * 2 + wm) * 128) * 512;
    const f16* bhp = (tensor ? wfhk : wfhq) + ((size_t)(oTile * 4 + wn * 2) * 128) * 512;
    const f16* blp = (tensor ? wflk : wflq) + ((size_t)(oTile * 4 + wn * 2) * 128) * 512;
    const float* src = (tensor ? K : Q) + (size_t)b * Hh * Ll * Dk;
    f16* dh = (tensor ? ffhk : ffhq);
    f16* dl = (tensor ? fflk : fflq);
    const float scale = tensor ? 1.f : QSCALE;
    const int klen16 = (*flag) << 5;            // 128 or 64 (even)

    f32x16 acc[2];
#pragma unroll
    for (int j = 0; j < 2; ++j)
#pragma unroll
        for (int r = 0; r < 16; ++r) acc[j][r] = 0.f;

    f16x8 Aah, Aal, Abh[2], Abl[2];             // buffer A
    f16x8 Bah, Bal, Bbh[2], Bbl[2];             // buffer B
    const size_t lo8 = (size_t)lane * 8;

    // prime buffer A with k16=0
    Aah = *(const f16x8*)(ah + lo8);
    Aal = *(const f16x8*)(al + lo8);
    Abh[0] = *(const f16x8*)(bhp + lo8);
    Abl[0] = *(const f16x8*)(blp + lo8);
    Abh[1] = *(const f16x8*)(bhp + 128 * 512 + lo8);
    Abl[1] = *(const f16x8*)(blp + 128 * 512 + lo8);

    for (int k16 = 0; k16 < klen16; k16 += 2) {
        {   // prefetch k16+1 into B
            int kn = k16 + 1 < klen16 ? k16 + 1 : k16;
            size_t o = (size_t)kn * 512 + lo8;
            Bah = *(const f16x8*)(ah + o);
            Bal = *(const f16x8*)(al + o);
            Bbh[0] = *(const f16x8*)(bhp + o);
            Bbl[0] = *(const f16x8*)(blp + o);
            Bbh[1] = *(const f16x8*)(bhp + 128 * 512 + o);
            Bbl[1] = *(const f16x8*)(blp + 128 * 512 + o);
        }
#pragma unroll
        for (int j = 0; j < 2; ++j) {
            acc[j] = MFMA32(Aah, Abh[j], acc[j]);
            acc[j] = MFMA32(Aah, Abl[j], acc[j]);
            acc[j] = MFMA32(Aal, Abh[j], acc[j]);
        }
        {   // prefetch k16+2 into A
            int kn = k16 + 2 < klen16 ? k16 + 2 : klen16 - 1;
            size_t o = (size_t)kn * 512 + lo8;
            Aah = *(const f16x8*)(ah + o);
            Aal = *(const f16x8*)(al + o);
            Abh[0] = *(const f16x8*)(bhp + o);
            Abl[0] = *(const f16x8*)(blp + o);
            Abh[1] = *(const f16x8*)(bhp + 128 * 512 + o);
            Abl[1] = *(const f16x8*)(blp + 128 * 512 + o);
        }
#pragma unroll
        for (int j = 0; j < 2; ++j) {
            acc[j] = MFMA32(Bah, Bbh[j], acc[j]);
            acc[j] = MFMA32(Bah, Bbl[j], acc[j]);
            acc[j] = MFMA32(Bal, Bbh[j], acc[j]);
        }
    }
    // epilogue: C[t][o] -> flat (h,l,d), add residual, scale, split, store in kattn frag order
#pragma unroll
    for (int j = 0; j < 2; ++j)
#pragma unroll
        for (int r = 0; r < 16; ++r) {
            int trow = tt * 64 + wm * 32 + (r & 3) + ((r >> 2) << 3) + (khalf << 2);
            int ocol = oTile * 128 + wn * 64 + j * 32 + lane31;
            int h = trow >> 8;
            int l = ((trow & 255) << 3) + (ocol >> 6);
            int d = ocol & 63;
            float v2 = (acc[j][r] + src[((size_t)h * Ll + l) * Dk + d]) * scale;
            f16 hi = (f16)v2;
            f16 lo = (f16)(v2 - (float)hi);
            size_t idx = ((((size_t)(b * 8 + h) * 64 + (l >> 5)) * 4 + (d >> 4)) * 64
                          + ((d >> 3) & 1) * 32 + (l & 31)) * 8 + (d & 7);
            dh[idx] = hi; dl[idx] = lo;
        }
}

// ---------------- F: fused attention, K-split across wave pairs ----------------
// R6: full residency. Grid is exactly 4 blocks/CU of work; previous variants capped
// residency at 2-3 -> tail generations ran underpopulated (Occupancy 21-26%).
// Superstep back to 4 ch (sbuf 34.8KB union'd) + __launch_bounds__(256,4):
// 4x34.8KB = 139KB LDS, one generation, zero tail. Burst store sweep kept (cached).
#define LOADK(DST, CH) do { size_t kb_ = (size_t)(CH) * 2048 + lane * 8;            \
    _Pragma("unroll") for (int ks_ = 0; ks_ < 4; ++ks_) {                           \
        DST[2 * ks_]     = *(const f16x8*)(kbh + kb_ + ks_ * 512);                  \
        DST[2 * ks_ + 1] = *(const f16x8*)(kbl + kb_ + ks_ * 512); } } while (0)

#define QKM(SRC, ACC) do { _Pragma("unroll") for (int ks_ = 0; ks_ < 4; ++ks_) {    \
        ACC = MFMA32(a_h[ks_], SRC[2 * ks_], ACC);                                  \
        ACC = MFMA32(a_h[ks_], SRC[2 * ks_ + 1], ACC);                              \
        ACC = MFMA32(a_l[ks_], SRC[2 * ks_], ACC); } } while (0)

#define SMUPD(ACC) do { _Pragma("unroll") for (int r_ = 0; r_ < 16; ++r_) {         \
        float v_ = ACC[r_]; float d_ = v_ - m[r_]; float e_ = exp2f(-fabsf(d_));    \
        bool gt_ = d_ > 0.f;                                                        \
        s[r_] = gt_ ? __fmaf_rn(s[r_], e_, 1.f) : (s[r_] + e_);                     \
        m[r_] = gt_ ? v_ : m[r_]; } } while (0)

#define LOADV(DST, CH) do { _Pragma("unroll") for (int q_ = 0; q_ < 4; ++q_) {      \
        int n_ = q_ >> 1, ks2_ = q_ & 1;                                            \
        size_t off_ = ((((size_t)bh * 2 + n_) * 128 + (CH) * 2 + ks2_) * 64 + lane) * 8; \
        DST[q_] = *(const f16x8*)(vf + off_); } } while (0)

union SMemU {
    float combuf[2][32][64];   // 16 KB exchange buffer (softmax combine, ctx reduce)
    f16 sbuf[4][32][136];      // 34.8 KB P stage: 272B rows (68w % 32 == 4,
                               // conflict-free b128 class, proven in R0/R3)
};

__global__ __launch_bounds__(256, 4) void kattn(
    const f16* __restrict__ qfh, const f16* __restrict__ qfl,
    const f16* __restrict__ kfh, const f16* __restrict__ kfl,
    const f16* __restrict__ vf,
    float* __restrict__ ctx_out, float* __restrict__ attn_out) {
    __shared__ __align__(16) SMemU sm;
    int id = blockIdx.x;                              // 1024; 4 bh per XCD for K/V L2 locality
    int bh = (id & 7) * 4 + (id >> 8);
    int qt = (id >> 3) & 31;
    int wave = threadIdx.x >> 6, lane = threadIdx.x & 63;
    int qg = wave >> 1, kg = wave & 1;
    int lane31 = lane & 31, khalf = lane >> 5;
    int q0 = qt * 64 + qg * 32;

    // resident Q fragments (hi/lo): 4 ksteps of 16 over d_k=64, contiguous 1KB loads
    f16x8 a_h[4], a_l[4];
    {
        size_t qb = ((size_t)bh * 64 + qt * 2 + qg) * 4;
#pragma unroll
        for (int ks = 0; ks < 4; ++ks) {
            a_h[ks] = *(const f16x8*)(qfh + ((qb + ks) * 64 + lane) * 8);
            a_l[ks] = *(const f16x8*)(qfl + ((qb + ks) * 64 + lane) * 8);
        }
    }
    const f16* kbh = kfh + (size_t)bh * 131072;
    const f16* kbl = kfl + (size_t)bh * 131072;
    const int ch0 = kg * 32, ch1 = ch0 + 32;

    float m[16], s[16];
#pragma unroll
    for (int r = 0; r < 16; ++r) { m[r] = -3.0e38f; s[r] = 0.f; }

    // ---- pass 1: online row max + sum of 2^z, K register ping-pong ----
    {
        f16x8 KA[8], KB[8];
        LOADK(KA, ch0);
        for (int ch = ch0; ch < ch1; ch += 2) {
            LOADK(KB, ch + 1);
            f32x16 acc;
#pragma unroll
            for (int r = 0; r < 16; ++r) acc[r] = 0.f;
            QKM(KA, acc);
            SMUPD(acc);
            {
                int chn = (ch + 2 < ch1) ? ch + 2 : ch;
                LOADK(KA, chn);
            }
            f32x16 acc2;
#pragma unroll
            for (int r = 0; r < 16; ++r) acc2[r] = 0.f;
            QKM(KB, acc2);
            SMUPD(acc2);
        }
    }
    // lane combine within the 32 col-lanes of each half
#pragma unroll
    for (int r = 0; r < 16; ++r) {
        float mm = m[r], ss = s[r];
#pragma unroll
        for (int off = 1; off < 32; off <<= 1) {
            float mo = __shfl_xor(mm, off, 64);
            float so = __shfl_xor(ss, off, 64);
            float mn = fmaxf(mm, mo);
            ss = ss * exp2f(mm - mn) + so * exp2f(mo - mn);
            mm = mn;
        }
        m[r] = mm; s[r] = ss;
    }
    // cross-wave (k-split) combine through LDS
    if (kg == 1) {
#pragma unroll
        for (int r = 0; r < 16; ++r) {
            sm.combuf[qg][r][lane] = m[r];
            sm.combuf[qg][16 + r][lane] = s[r];
        }
    }
    __syncthreads();
    if (kg == 0) {
#pragma unroll
        for (int r = 0; r < 16; ++r) {
            float m1 = sm.combuf[qg][r][lane];
            float s1 = sm.combuf[qg][16 + r][lane];
            float mn = fmaxf(m[r], m1);
            float ss = s[r] * exp2f(m[r] - mn) + s1 * exp2f(m1 - mn);
            m[r] = mn; s[r] = 1.f / ss;
            sm.combuf[qg][r][lane] = mn;
            sm.combuf[qg][16 + r][lane] = s[r];
        }
    }
    __syncthreads();
    if (kg == 1) {
#pragma unroll
        for (int r = 0; r < 16; ++r) {
            m[r] = sm.combuf[qg][r][lane];
            s[r] = sm.combuf[qg][16 + r][lane];
        }
    }
    __syncthreads();   // union hazard: combuf reads must finish before sbuf writes

    f32x16 ctx[2];
#pragma unroll
    for (int n = 0; n < 2; ++n)
#pragma unroll
        for (int r = 0; r < 16; ++r) ctx[n][r] = 0.f;

    const size_t rowbase = ((size_t)bh * Ll + q0) * Ll;

    // ---- pass 2: recompute scores (identical op order), stage P in LDS, PV,
    //      then sweep 128-col batches to attn_out as 512B-per-row bursts ----
    {
        f16x8 KV[8], VV[4];
        LOADK(KV, ch0);
        LOADV(VV, ch0);
        for (int chb = ch0; chb < ch1; chb += 4) {
#pragma unroll
            for (int i = 0; i < 4; ++i) {
                int ch = chb + i;
                f32x16 acc;
#pragma unroll
                for (int r = 0; r < 16; ++r) acc[r] = 0.f;
                QKM(KV, acc);
                int chn = (ch + 1 < ch1) ? ch + 1 : ch;
                LOADK(KV, chn);              // WAR on KV: safe after MFMA issue; covered by tail
#pragma unroll
                for (int r = 0; r < 16; ++r) {
                    float p = exp2f(acc[r] - m[r]) * s[r];
                    int row = (r & 3) + ((r >> 2) << 3) + (khalf << 2);
                    sm.sbuf[wave][row][i * 32 + lane31] = (f16)p;
                }
                __asm__ volatile("s_waitcnt lgkmcnt(0)" ::: "memory");  // wave-private LDS RAW
#pragma unroll
                for (int ks2 = 0; ks2 < 2; ++ks2) {
                    f16x8 pa = *(const f16x8*)&sm.sbuf[wave][lane31][i * 32 + ks2 * 16 + khalf * 8];
                    ctx[0] = MFMA32(pa, VV[ks2], ctx[0]);
                    ctx[1] = MFMA32(pa, VV[2 + ks2], ctx[1]);
                }
                LOADV(VV, chn);              // covered by next QK cluster
            }
            // store sweep: 32 rows x 128 cols, 512B contiguous per row, cached stores
#pragma unroll
            for (int ri = 0; ri < 16; ++ri) {
                int row = ri * 2 + khalf;
                f16x4 pv = *(const f16x4*)&sm.sbuf[wave][row][lane31 * 4];
                f32x4 o = {(float)pv[0], (float)pv[1], (float)pv[2], (float)pv[3]};
                *(f32x4*)(attn_out + rowbase + (size_t)row * Ll + chb * 32 + lane31 * 4) = o;
            }
        }
    }
    // ---- k-split ctx reduction ----
    __syncthreads();
    if (kg == 1) {
#pragma unroll
        for (int n = 0; n < 2; ++n)
#pragma unroll
            for (int r = 0; r < 16; ++r) sm.combuf[qg][n * 16 + r][lane] = ctx[n][r];
    }
    __syncthreads();
    if (kg == 0) {
#pragma unroll
        for (int n = 0; n < 2; ++n)
#pragma unroll
            for (int r = 0; r < 16; ++r) {
                float v = ctx[n][r] + sm.combuf[qg][n * 16 + r][lane];
                int row = (r & 3) + ((r >> 2) << 3) + (khalf << 2);
                ctx_out[((size_t)bh * Ll + q0 + row) * Dk + n * 32 + lane31] = v;
            }
    }
}

extern "C" void kernel_launch(void* const* d_in, const int* in_sizes, int n_in,
                              void* d_out, int out_size, void* d_ws, size_t ws_size,
                              hipStream_t stream) {
    const float* Q = (const float*)d_in[0];
    const float* K = (const float*)d_in[1];
    const float* V = (const float*)d_in[2];
    // d_in[3] = attn_mask (all-false, unused)
    const float* convq = (const float*)d_in[4];
    const float* convk = (const float*)d_in[5];
    const float* w = (const float*)d_in[6];

    char* ws = (char*)d_ws;
    int* flag = (int*)ws;
    f16* wfhq = (f16*)(ws + OFF_WF);
    f16* wflq = wfhq + NWF;
    f16* wfhk = wflq + NWF;
    f16* wflk = wfhk + NWF;
    f16* afhq = (f16*)(ws + OFF_AF);
    f16* aflq = afhq + NAF;
    f16* afhk = aflq + NAF;
    f16* aflk = afhk + NAF;
    f16* ffhq = (f16*)(ws + OFF_FF);
    f16* fflq = ffhq + NFF;
    f16* ffhk = fflq + NFF;
    f16* fflk = ffhk + NFF;
    f16* vf = (f16*)(ws + OFF_VF);

    float* ctx_out = (float*)d_out;
    float* attn_out = ctx_out + (size_t)BH * Ll * Dk;

    kprep_w<<<dim3(1024, 2), 256, 0, stream>>>(convq, convk, w, flag, wfhq, wflq, wfhk, wflk);
    kprep_v<<<dim3(16, 32), 256, 0, stream>>>(V, vf);
    kprep_a<<<dim3(2048, 4, 2), 256, 0, stream>>>(Q, K, flag, afhq, aflq, afhk, aflk);
    kconv<<<dim3(1024), 256, 0, stream>>>(Q, K, flag, afhq, aflq, afhk, aflk,
                                          wfhq, wflq, wfhk, wflk, ffhq, fflq, ffhk, fflk);
    kattn<<<dim3(1024), 256, 0, stream>>>(ffhq, fflq, ffhk, fflk, vf, ctx_out, attn_out);
}

// Round 7
// 1145.480 us; speedup vs baseline: 1.1818x; 1.1818x over previous
//
#include <hip/hip_runtime.h>

typedef _Float16 f16;
typedef _Float16 f16x4 __attribute__((ext_vector_type(4)));
typedef _Float16 f16x8 __attribute__((ext_vector_type(8)));
typedef float f32x4 __attribute__((ext_vector_type(4)));
typedef float f32x16 __attribute__((ext_vector_type(16)));

#define MFMA32(A, B, C) __builtin_amdgcn_mfma_f32_32x32x16_f16(A, B, C, 0, 0, 0)

constexpr int Bb = 4, Hh = 8, Ll = 2048, Dk = 64, Dm = 512, BH = 32;

// element counts per (tensor,hilo) array
constexpr size_t NWF = (size_t)16 * 128 * 64 * 8;      // W frag: [ob16][k16:128][lane][8]
constexpr size_t NAF = (size_t)Bb * 64 * 128 * 64 * 8; // A frag: [b][tb64][k16:128][lane][8]
constexpr size_t NFF = (size_t)BH * 64 * 4 * 64 * 8;   // Qc/Kc frag: [bh][lb64][d16:4][lane][8]
constexpr size_t NVF = (size_t)BH * 2 * 128 * 64 * 8;  // V frag: [bh][db2][l16:128][lane][8]

constexpr size_t OFF_WF = 256;
constexpr size_t OFF_AF = OFF_WF + 4 * NWF * sizeof(f16);
constexpr size_t OFF_FF = OFF_AF + 4 * NAF * sizeof(f16);
constexpr size_t OFF_VF = OFF_FF + 4 * NFF * sizeof(f16);

// scores computed in base-2: fold log2(e)/sqrt(64) into Qc (exact softmax identity)
#define QSCALE 0.1803368801111204f

// ---------------- P1: mask + split conv weights into frag order ----------------
__global__ void kprep_w(const float* __restrict__ convq, const float* __restrict__ convk,
                        const float* __restrict__ w, int* __restrict__ flag,
                        f16* __restrict__ wfhq, f16* __restrict__ wflq,
                        f16* __restrict__ wfhk, f16* __restrict__ wflk) {
    const int len = (4.f * w[1] > 2.f * w[0]) ? 4 : 2;   // argmax([2w0,4w1]) -> FILTER_LENGTHS[ind]
    if (blockIdx.x == 0 && blockIdx.y == 0 && threadIdx.x == 0) *flag = len;
    int tid = blockIdx.x * 256 + threadIdx.x;            // 0..262143 = c*512+o
    int o = tid & 511;
    const float* conv = blockIdx.y ? convk : convq;
    f16* dh = blockIdx.y ? wfhk : wfhq;
    f16* dl = blockIdx.y ? wflk : wflq;
    const float4 v = *(const float4*)(conv + (size_t)tid * 4);  // conv[c][o][0..3]
    float vv[4] = {v.x, v.y, v.z, v.w};
    int c = tid >> 9, ob = o >> 5;
#pragma unroll
    for (int f = 0; f < 4; ++f) {
        float x = (f < len) ? vv[f] : 0.f;
        f16 hi = (f16)x;
        f16 lo = (f16)(x - (float)hi);
        int k = (f << 9) + c;
        size_t idx = (((size_t)ob * 128 + (k >> 4)) * 64 + ((k >> 3) & 1) * 32 + (o & 31)) * 8 + (k & 7);
        dh[idx] = hi; dl[idx] = lo;
    }
}

// ---------------- P2: conv A operand, frag order, f-shift baked in ----------------
__global__ void kprep_a(const float* __restrict__ Q, const float* __restrict__ K,
                        const int* __restrict__ flag,
                        f16* __restrict__ afhq, f16* __restrict__ aflq,
                        f16* __restrict__ afhk, f16* __restrict__ aflk) {
    __shared__ float tile[64][36];
    int tensor = blockIdx.z, b = blockIdx.y;
    int tb = blockIdx.x >> 5, k16g = blockIdx.x & 31;
    int f = k16g >> 3;                       // constant over the block's 64 k's
    if (f >= *flag) return;                  // masked f: weights are zero and kconv never reads
    int c0 = (k16g * 64) & 511;
    const float* S = (tensor ? K : Q) + (size_t)b * Dm * Ll;  // flat b x 512 x 2048 view
    int tid = threadIdx.x;
    int t0 = tb * 32;
#pragma unroll
    for (int i = 0; i < 9; ++i) {
        int e = i * 256 + tid;               // 0..2303
        int row = e / 36, col = e - row * 36;
        int t = t0 - 2 + col;
        tile[row][col] = (t >= 0 && t < Ll) ? S[(size_t)(c0 + row) * Ll + t] : 0.f;
    }
    __syncthreads();
    int sub = tid >> 6, lane = tid & 63;
    int k16 = k16g * 4 + sub;
    int khalf = lane >> 5, lane31 = lane & 31;
    f16x8 hv, lv;
#pragma unroll
    for (int j = 0; j < 8; ++j) {
        int cl = sub * 16 + khalf * 8 + j;
        float x = tile[cl][lane31 + f];
        f16 hi = (f16)x;
        hv[j] = hi; lv[j] = (f16)(x - (float)hi);
    }
    f16* dh = tensor ? afhk : afhq;
    f16* dl = tensor ? aflk : aflq;
    size_t idx = ((((size_t)b * 64 + tb) * 128 + k16) * 64 + lane) * 8;
    *(f16x8*)(dh + idx) = hv;
    *(f16x8*)(dl + idx) = lv;
}

// ---------------- P3: V -> frag order for PV B-operand ----------------
__global__ void kprep_v(const float* __restrict__ V, f16* __restrict__ vf) {
    int bh = blockIdx.y, l0 = blockIdx.x * 128;
    int tid = threadIdx.x;
    const float* src = V + (size_t)bh * Ll * Dk;
#pragma unroll
    for (int s = 0; s < 4; ++s) {
        int g = s * 4 + (tid >> 6);
        int lane = tid & 63;
        int l16s = g >> 1, db = g & 1;
        int khalf = lane >> 5, lane31 = lane & 31;
        int d = db * 32 + lane31;
        f16x8 out;
#pragma unroll
        for (int j = 0; j < 8; ++j) {
            int l = l0 + l16s * 16 + khalf * 8 + j;
            out[j] = (f16)src[(size_t)l * Dk + d];
        }
        size_t idx = ((((size_t)bh * 2 + db) * 128 + (l0 >> 4) + l16s) * 64 + lane) * 8;
        *(f16x8*)(vf + idx) = out;
    }
}

// ---------------- C: conv GEMM, 1024 blocks, ping-pong pipelined frag loads ----------------
__global__ __launch_bounds__(256, 4) void kconv(
    const float* __restrict__ Q, const float* __restrict__ K, const int* __restrict__ flag,
    const f16* __restrict__ afhq, const f16* __restrict__ aflq,
    const f16* __restrict__ afhk, const f16* __restrict__ aflk,
    const f16* __restrict__ wfhq, const f16* __restrict__ wflq,
    const f16* __restrict__ wfhk, const f16* __restrict__ wflk,
    f16* __restrict__ ffhq, f16* __restrict__ fflq,
    f16* __restrict__ ffhk, f16* __restrict__ fflk) {
    int id = blockIdx.x;                        // XCD swizzle: 4 oTile-siblings share id&7
    int xcd = id & 7, oTile = (id >> 3) & 3, gidx = id >> 5;
    int g = gidx * 8 + xcd;
    int tt = g & 31, b = (g >> 5) & 3, tensor = (g >> 7) & 1;
    int wave = threadIdx.x >> 6, lane = threadIdx.x & 63;
    int wn = wave & 1, wm = wave >> 1;
    int lane31 = lane & 31, khalf = lane >> 5;
    const f16* ah = (tensor ? afhk : afhq) + ((size_t)(b * 64 + tt * 2 + wm) * 128) * 512;
    const f16* al = (tensor ? aflk : aflq) + ((size_t)(b * 64 + tt * 2 + wm) * 128) * 512;
    const f16* bhp = (tensor ? wfhk : wfhq) + ((size_t)(oTile * 4 + wn * 2) * 128) * 512;
    const f16* blp = (tensor ? wflk : wflq) + ((size_t)(oTile * 4 + wn * 2) * 128) * 512;
    const float* src = (tensor ? K : Q) + (size_t)b * Hh * Ll * Dk;
    f16* dh = (tensor ? ffhk : ffhq);
    f16* dl = (tensor ? fflk : fflq);
    const float scale = tensor ? 1.f : QSCALE;
    const int klen16 = (*flag) << 5;            // 128 or 64 (even)

    f32x16 acc[2];
#pragma unroll
    for (int j = 0; j < 2; ++j)
#pragma unroll
        for (int r = 0; r < 16; ++r) acc[j][r] = 0.f;

    f16x8 Aah, Aal, Abh[2], Abl[2];             // buffer A
    f16x8 Bah, Bal, Bbh[2], Bbl[2];             // buffer B
    const size_t lo8 = (size_t)lane * 8;

    // prime buffer A with k16=0
    Aah = *(const f16x8*)(ah + lo8);
    Aal = *(const f16x8*)(al + lo8);
    Abh[0] = *(const f16x8*)(bhp + lo8);
    Abl[0] = *(const f16x8*)(blp + lo8);
    Abh[1] = *(const f16x8*)(bhp + 128 * 512 + lo8);
    Abl[1] = *(const f16x8*)(blp + 128 * 512 + lo8);

    for (int k16 = 0; k16 < klen16; k16 += 2) {
        {   // prefetch k16+1 into B
            int kn = k16 + 1 < klen16 ? k16 + 1 : k16;
            size_t o = (size_t)kn * 512 + lo8;
            Bah = *(const f16x8*)(ah + o);
            Bal = *(const f16x8*)(al + o);
            Bbh[0] = *(const f16x8*)(bhp + o);
            Bbl[0] = *(const f16x8*)(blp + o);
            Bbh[1] = *(const f16x8*)(bhp + 128 * 512 + o);
            Bbl[1] = *(const f16x8*)(blp + 128 * 512 + o);
        }
#pragma unroll
        for (int j = 0; j < 2; ++j) {
            acc[j] = MFMA32(Aah, Abh[j], acc[j]);
            acc[j] = MFMA32(Aah, Abl[j], acc[j]);
            acc[j] = MFMA32(Aal, Abh[j], acc[j]);
        }
        {   // prefetch k16+2 into A
            int kn = k16 + 2 < klen16 ? k16 + 2 : klen16 - 1;
            size_t o = (size_t)kn * 512 + lo8;
            Aah = *(const f16x8*)(ah + o);
            Aal = *(const f16x8*)(al + o);
            Abh[0] = *(const f16x8*)(bhp + o);
            Abl[0] = *(const f16x8*)(blp + o);
            Abh[1] = *(const f16x8*)(bhp + 128 * 512 + o);
            Abl[1] = *(const f16x8*)(blp + 128 * 512 + o);
        }
#pragma unroll
        for (int j = 0; j < 2; ++j) {
            acc[j] = MFMA32(Bah, Bbh[j], acc[j]);
            acc[j] = MFMA32(Bah, Bbl[j], acc[j]);
            acc[j] = MFMA32(Bal, Bbh[j], acc[j]);
        }
    }
    // epilogue: C[t][o] -> flat (h,l,d), add residual, scale, split, store in kattn frag order
#pragma unroll
    for (int j = 0; j < 2; ++j)
#pragma unroll
        for (int r = 0; r < 16; ++r) {
            int trow = tt * 64 + wm * 32 + (r & 3) + ((r >> 2) << 3) + (khalf << 2);
            int ocol = oTile * 128 + wn * 64 + j * 32 + lane31;
            int h = trow >> 8;
            int l = ((trow & 255) << 3) + (ocol >> 6);
            int d = ocol & 63;
            float v2 = (acc[j][r] + src[((size_t)h * Ll + l) * Dk + d]) * scale;
            f16 hi = (f16)v2;
            f16 lo = (f16)(v2 - (float)hi);
            size_t idx = ((((size_t)(b * 8 + h) * 64 + (l >> 5)) * 4 + (d >> 4)) * 64
                          + ((d >> 3) & 1) * 32 + (l & 31)) * 8 + (d & 7);
            dh[idx] = hi; dl[idx] = lo;
        }
}

// ---------------- F: fused attention, K-split across wave pairs ----------------
// R7 == R6 body with __launch_bounds__(256,3): R6's (256,4) forced VGPR to 64 ->
// scratch spills (FETCH 1.1GB, WRITE 1.46GB of spill traffic). 3 blocks/CU needs
// <=170 VGPR (fits, kernel wants ~100-128) and 3x34.8KB=104KB LDS (fits 160KB).
// Tests {3 blk/CU x no-spill x burst-stores}, the unexplored corner.
#define LOADK(DST, CH) do { size_t kb_ = (size_t)(CH) * 2048 + lane * 8;            \
    _Pragma("unroll") for (int ks_ = 0; ks_ < 4; ++ks_) {                           \
        DST[2 * ks_]     = *(const f16x8*)(kbh + kb_ + ks_ * 512);                  \
        DST[2 * ks_ + 1] = *(const f16x8*)(kbl + kb_ + ks_ * 512); } } while (0)

#define QKM(SRC, ACC) do { _Pragma("unroll") for (int ks_ = 0; ks_ < 4; ++ks_) {    \
        ACC = MFMA32(a_h[ks_], SRC[2 * ks_], ACC);                                  \
        ACC = MFMA32(a_h[ks_], SRC[2 * ks_ + 1], ACC);                              \
        ACC = MFMA32(a_l[ks_], SRC[2 * ks_], ACC); } } while (0)

#define SMUPD(ACC) do { _Pragma("unroll") for (int r_ = 0; r_ < 16; ++r_) {         \
        float v_ = ACC[r_]; float d_ = v_ - m[r_]; float e_ = exp2f(-fabsf(d_));    \
        bool gt_ = d_ > 0.f;                                                        \
        s[r_] = gt_ ? __fmaf_rn(s[r_], e_, 1.f) : (s[r_] + e_);                     \
        m[r_] = gt_ ? v_ : m[r_]; } } while (0)

#define LOADV(DST, CH) do { _Pragma("unroll") for (int q_ = 0; q_ < 4; ++q_) {      \
        int n_ = q_ >> 1, ks2_ = q_ & 1;                                            \
        size_t off_ = ((((size_t)bh * 2 + n_) * 128 + (CH) * 2 + ks2_) * 64 + lane) * 8; \
        DST[q_] = *(const f16x8*)(vf + off_); } } while (0)

union SMemU {
    float combuf[2][32][64];   // 16 KB exchange buffer (softmax combine, ctx reduce)
    f16 sbuf[4][32][136];      // 34.8 KB P stage: 272B rows (68w % 32 == 4,
                               // conflict-free b128 class, proven in R0/R3)
};

__global__ __launch_bounds__(256, 3) void kattn(
    const f16* __restrict__ qfh, const f16* __restrict__ qfl,
    const f16* __restrict__ kfh, const f16* __restrict__ kfl,
    const f16* __restrict__ vf,
    float* __restrict__ ctx_out, float* __restrict__ attn_out) {
    __shared__ __align__(16) SMemU sm;
    int id = blockIdx.x;                              // 1024; 4 bh per XCD for K/V L2 locality
    int bh = (id & 7) * 4 + (id >> 8);
    int qt = (id >> 3) & 31;
    int wave = threadIdx.x >> 6, lane = threadIdx.x & 63;
    int qg = wave >> 1, kg = wave & 1;
    int lane31 = lane & 31, khalf = lane >> 5;
    int q0 = qt * 64 + qg * 32;

    // resident Q fragments (hi/lo): 4 ksteps of 16 over d_k=64, contiguous 1KB loads
    f16x8 a_h[4], a_l[4];
    {
        size_t qb = ((size_t)bh * 64 + qt * 2 + qg) * 4;
#pragma unroll
        for (int ks = 0; ks < 4; ++ks) {
            a_h[ks] = *(const f16x8*)(qfh + ((qb + ks) * 64 + lane) * 8);
            a_l[ks] = *(const f16x8*)(qfl + ((qb + ks) * 64 + lane) * 8);
        }
    }
    const f16* kbh = kfh + (size_t)bh * 131072;
    const f16* kbl = kfl + (size_t)bh * 131072;
    const int ch0 = kg * 32, ch1 = ch0 + 32;

    float m[16], s[16];
#pragma unroll
    for (int r = 0; r < 16; ++r) { m[r] = -3.0e38f; s[r] = 0.f; }

    // ---- pass 1: online row max + sum of 2^z, K register ping-pong ----
    {
        f16x8 KA[8], KB[8];
        LOADK(KA, ch0);
        for (int ch = ch0; ch < ch1; ch += 2) {
            LOADK(KB, ch + 1);
            f32x16 acc;
#pragma unroll
            for (int r = 0; r < 16; ++r) acc[r] = 0.f;
            QKM(KA, acc);
            SMUPD(acc);
            {
                int chn = (ch + 2 < ch1) ? ch + 2 : ch;
                LOADK(KA, chn);
            }
            f32x16 acc2;
#pragma unroll
            for (int r = 0; r < 16; ++r) acc2[r] = 0.f;
            QKM(KB, acc2);
            SMUPD(acc2);
        }
    }
    // lane combine within the 32 col-lanes of each half
#pragma unroll
    for (int r = 0; r < 16; ++r) {
        float mm = m[r], ss = s[r];
#pragma unroll
        for (int off = 1; off < 32; off <<= 1) {
            float mo = __shfl_xor(mm, off, 64);
            float so = __shfl_xor(ss, off, 64);
            float mn = fmaxf(mm, mo);
            ss = ss * exp2f(mm - mn) + so * exp2f(mo - mn);
            mm = mn;
        }
        m[r] = mm; s[r] = ss;
    }
    // cross-wave (k-split) combine through LDS
    if (kg == 1) {
#pragma unroll
        for (int r = 0; r < 16; ++r) {
            sm.combuf[qg][r][lane] = m[r];
            sm.combuf[qg][16 + r][lane] = s[r];
        }
    }
    __syncthreads();
    if (kg == 0) {
#pragma unroll
        for (int r = 0; r < 16; ++r) {
            float m1 = sm.combuf[qg][r][lane];
            float s1 = sm.combuf[qg][16 + r][lane];
            float mn = fmaxf(m[r], m1);
            float ss = s[r] * exp2f(m[r] - mn) + s1 * exp2f(m1 - mn);
            m[r] = mn; s[r] = 1.f / ss;
            sm.combuf[qg][r][lane] = mn;
            sm.combuf[qg][16 + r][lane] = s[r];
        }
    }
    __syncthreads();
    if (kg == 1) {
#pragma unroll
        for (int r = 0; r < 16; ++r) {
            m[r] = sm.combuf[qg][r][lane];
            s[r] = sm.combuf[qg][16 + r][lane];
        }
    }
    __syncthreads();   // union hazard: combuf reads must finish before sbuf writes

    f32x16 ctx[2];
#pragma unroll
    for (int n = 0; n < 2; ++n)
#pragma unroll
        for (int r = 0; r < 16; ++r) ctx[n][r] = 0.f;

    const size_t rowbase = ((size_t)bh * Ll + q0) * Ll;

    // ---- pass 2: recompute scores (identical op order), stage P in LDS, PV,
    //      then sweep 128-col batches to attn_out as 512B-per-row bursts ----
    {
        f16x8 KV[8], VV[4];
        LOADK(KV, ch0);
        LOADV(VV, ch0);
        for (int chb = ch0; chb < ch1; chb += 4) {
#pragma unroll
            for (int i = 0; i < 4; ++i) {
                int ch = chb + i;
                f32x16 acc;
#pragma unroll
                for (int r = 0; r < 16; ++r) acc[r] = 0.f;
                QKM(KV, acc);
                int chn = (ch + 1 < ch1) ? ch + 1 : ch;
                LOADK(KV, chn);              // WAR on KV: safe after MFMA issue; covered by tail
#pragma unroll
                for (int r = 0; r < 16; ++r) {
                    float p = exp2f(acc[r] - m[r]) * s[r];
                    int row = (r & 3) + ((r >> 2) << 3) + (khalf << 2);
                    sm.sbuf[wave][row][i * 32 + lane31] = (f16)p;
                }
                __asm__ volatile("s_waitcnt lgkmcnt(0)" ::: "memory");  // wave-private LDS RAW
#pragma unroll
                for (int ks2 = 0; ks2 < 2; ++ks2) {
                    f16x8 pa = *(const f16x8*)&sm.sbuf[wave][lane31][i * 32 + ks2 * 16 + khalf * 8];
                    ctx[0] = MFMA32(pa, VV[ks2], ctx[0]);
                    ctx[1] = MFMA32(pa, VV[2 + ks2], ctx[1]);
                }
                LOADV(VV, chn);              // covered by next QK cluster
            }
            // store sweep: 32 rows x 128 cols, 512B contiguous per row, cached stores
#pragma unroll
            for (int ri = 0; ri < 16; ++ri) {
                int row = ri * 2 + khalf;
                f16x4 pv = *(const f16x4*)&sm.sbuf[wave][row][lane31 * 4];
                f32x4 o = {(float)pv[0], (float)pv[1], (float)pv[2], (float)pv[3]};
                *(f32x4*)(attn_out + rowbase + (size_t)row * Ll + chb * 32 + lane31 * 4) = o;
            }
        }
    }
    // ---- k-split ctx reduction ----
    __syncthreads();
    if (kg == 1) {
#pragma unroll
        for (int n = 0; n < 2; ++n)
#pragma unroll
            for (int r = 0; r < 16; ++r) sm.combuf[qg][n * 16 + r][lane] = ctx[n][r];
    }
    __syncthreads();
    if (kg == 0) {
#pragma unroll
        for (int n = 0; n < 2; ++n)
#pragma unroll
            for (int r = 0; r < 16; ++r) {
                float v = ctx[n][r] + sm.combuf[qg][n * 16 + r][lane];
                int row = (r & 3) + ((r >> 2) << 3) + (khalf << 2);
                ctx_out[((size_t)bh * Ll + q0 + row) * Dk + n * 32 + lane31] = v;
            }
    }
}

extern "C" void kernel_launch(void* const* d_in, const int* in_sizes, int n_in,
                              void* d_out, int out_size, void* d_ws, size_t ws_size,
                              hipStream_t stream) {
    const float* Q = (const float*)d_in[0];
    const float* K = (const float*)d_in[1];
    const float* V = (const float*)d_in[2];
    // d_in[3] = attn_mask (all-false, unused)
    const float* convq = (const float*)d_in[4];
    const float* convk = (const float*)d_in[5];
    const float* w = (const float*)d_in[6];

    char* ws = (char*)d_ws;
    int* flag = (int*)ws;
    f16* wfhq = (f16*)(ws + OFF_WF);
    f16* wflq = wfhq + NWF;
    f16* wfhk = wflq + NWF;
    f16* wflk = wfhk + NWF;
    f16* afhq = (f16*)(ws + OFF_AF);
    f16* aflq = afhq + NAF;
    f16* afhk = aflq + NAF;
    f16* aflk = afhk + NAF;
    f16* ffhq = (f16*)(ws + OFF_FF);
    f16* fflq = ffhq + NFF;
    f16* ffhk = fflq + NFF;
    f16* fflk = ffhk + NFF;
    f16* vf = (f16*)(ws + OFF_VF);

    float* ctx_out = (float*)d_out;
    float* attn_out = ctx_out + (size_t)BH * Ll * Dk;

    kprep_w<<<dim3(1024, 2), 256, 0, stream>>>(convq, convk, w, flag, wfhq, wflq, wfhk, wflk);
    kprep_v<<<dim3(16, 32), 256, 0, stream>>>(V, vf);
    kprep_a<<<dim3(2048, 4, 2), 256, 0, stream>>>(Q, K, flag, afhq, aflq, afhk, aflk);
    kconv<<<dim3(1024), 256, 0, stream>>>(Q, K, flag, afhq, aflq, afhk, aflk,
                                          wfhq, wflq, wfhk, wflk, ffhq, fflq, ffhk, fflk);
    kattn<<<dim3(1024), 256, 0, stream>>>(ffhq, fflq, ffhk, fflk, vf, ctx_out, attn_out);
}

// Round 8
// 993.930 us; speedup vs baseline: 1.3620x; 1.1525x over previous
//
#include <hip/hip_runtime.h>

typedef _Float16 f16;
typedef _Float16 f16x4 __attribute__((ext_vector_type(4)));
typedef _Float16 f16x8 __attribute__((ext_vector_type(8)));
typedef float f32x4 __attribute__((ext_vector_type(4)));
typedef float f32x16 __attribute__((ext_vector_type(16)));

#define MFMA32(A, B, C) __builtin_amdgcn_mfma_f32_32x32x16_f16(A, B, C, 0, 0, 0)

constexpr int Bb = 4, Hh = 8, Ll = 2048, Dk = 64, Dm = 512, BH = 32;

// element counts per (tensor,hilo) array
constexpr size_t NWF = (size_t)16 * 128 * 64 * 8;      // W frag: [ob16][k16:128][lane][8]
constexpr size_t NAF = (size_t)Bb * 64 * 128 * 64 * 8; // A frag: [b][tb64][k16:128][lane][8]
constexpr size_t NFF = (size_t)BH * 64 * 4 * 64 * 8;   // Qc/Kc frag: [bh][lb64][d16:4][lane][8]
constexpr size_t NVF = (size_t)BH * 2 * 128 * 64 * 8;  // V frag: [bh][db2][l16:128][lane][8]

constexpr size_t OFF_WF = 256;
constexpr size_t OFF_AF = OFF_WF + 4 * NWF * sizeof(f16);
constexpr size_t OFF_FF = OFF_AF + 4 * NAF * sizeof(f16);
constexpr size_t OFF_VF = OFF_FF + 4 * NFF * sizeof(f16);

// scores computed in base-2: fold log2(e)/sqrt(64) into Qc (exact softmax identity)
#define QSCALE 0.1803368801111204f

// ---------------- P1: mask + split conv weights into frag order ----------------
// R8: thread owns 8 consecutive c for one o -> the 8 (k&7) slots of one f16x8
// -> contiguous 16B writes (512B/wave-instr). Old version: scalar 2B scattered
// stores whose line-mates lived in other blocks (partial-line RFO amplification).
__global__ void kprep_w(const float* __restrict__ convq, const float* __restrict__ convk,
                        const float* __restrict__ w, int* __restrict__ flag,
                        f16* __restrict__ wfhq, f16* __restrict__ wflq,
                        f16* __restrict__ wfhk, f16* __restrict__ wflk) {
    const int len = (4.f * w[1] > 2.f * w[0]) ? 4 : 2;   // argmax([2w0,4w1]) -> FILTER_LENGTHS[ind]
    if (blockIdx.x == 0 && blockIdx.y == 0 && threadIdx.x == 0) *flag = len;
    int g = blockIdx.x * 256 + threadIdx.x;              // [0,32768) = c8*512 + o
    int o = g & 511, c8 = g >> 9;                        // c = c8*8 + cc
    const float* conv = blockIdx.y ? convk : convq;
    f16* dh = blockIdx.y ? wfhk : wfhq;
    f16* dl = blockIdx.y ? wflk : wflq;
    float4 v[8];
#pragma unroll
    for (int cc = 0; cc < 8; ++cc)                       // coalesced: lanes read consecutive float4
        v[cc] = *(const float4*)(conv + ((size_t)(c8 * 8 + cc) * 512 + o) * 4);
    int ob = o >> 5;
#pragma unroll
    for (int f = 0; f < 4; ++f) {
        f16x8 hv, lv;
#pragma unroll
        for (int cc = 0; cc < 8; ++cc) {
            float x = (f < len) ? ((const float*)&v[cc])[f] : 0.f;
            f16 hi = (f16)x;
            hv[cc] = hi; lv[cc] = (f16)(x - (float)hi);
        }
        // k = f*512 + c8*8 + cc: k&7=cc, (k>>3)&1=c8&1, k16=f*32+(c8>>1)
        int k16 = f * 32 + (c8 >> 1);
        size_t base = (((size_t)ob * 128 + k16) * 64 + (c8 & 1) * 32 + (o & 31)) * 8;
        *(f16x8*)(dh + base) = hv;
        *(f16x8*)(dl + base) = lv;
    }
}

// ---------------- P2: conv A operand, frag order, f-shift baked in ----------------
// R8: one block computes ALL f-planes from a single 64x36 tile load (old version
// launched 4x the blocks, re-reading Q/K once per filter tap).
__global__ void kprep_a(const float* __restrict__ Q, const float* __restrict__ K,
                        const int* __restrict__ flag,
                        f16* __restrict__ afhq, f16* __restrict__ aflq,
                        f16* __restrict__ afhk, f16* __restrict__ aflk) {
    __shared__ float tile[64][36];
    int tensor = blockIdx.z, b = blockIdx.y;
    int tb = blockIdx.x >> 3, crange = blockIdx.x & 7;
    int c0 = crange * 64;
    const int flen = *flag;
    const float* S = (tensor ? K : Q) + (size_t)b * Dm * Ll;  // flat b x 512 x 2048 view
    int tid = threadIdx.x;
    int t0 = tb * 32;
#pragma unroll
    for (int i = 0; i < 9; ++i) {
        int e = i * 256 + tid;               // 0..2303
        int row = e / 36, col = e - row * 36;
        int t = t0 - 2 + col;
        tile[row][col] = (t >= 0 && t < Ll) ? S[(size_t)(c0 + row) * Ll + t] : 0.f;
    }
    __syncthreads();
    int sub = tid >> 6, lane = tid & 63;
    int khalf = lane >> 5, lane31 = lane & 31;
    f16* dh = tensor ? afhk : afhq;
    f16* dl = tensor ? aflk : aflq;
    for (int f = 0; f < flen; ++f) {
        int k16 = (f * 8 + crange) * 4 + sub;
        f16x8 hv, lv;
#pragma unroll
        for (int j = 0; j < 8; ++j) {
            int cl = sub * 16 + khalf * 8 + j;
            float x = tile[cl][lane31 + f];
            f16 hi = (f16)x;
            hv[j] = hi; lv[j] = (f16)(x - (float)hi);
        }
        size_t idx = ((((size_t)b * 64 + tb) * 128 + k16) * 64 + lane) * 8;
        *(f16x8*)(dh + idx) = hv;
        *(f16x8*)(dl + idx) = lv;
    }
}

// ---------------- P3: V -> frag order for PV B-operand ----------------
__global__ void kprep_v(const float* __restrict__ V, f16* __restrict__ vf) {
    int bh = blockIdx.y, l0 = blockIdx.x * 128;
    int tid = threadIdx.x;
    const float* src = V + (size_t)bh * Ll * Dk;
#pragma unroll
    for (int s = 0; s < 4; ++s) {
        int g = s * 4 + (tid >> 6);
        int lane = tid & 63;
        int l16s = g >> 1, db = g & 1;
        int khalf = lane >> 5, lane31 = lane & 31;
        int d = db * 32 + lane31;
        f16x8 out;
#pragma unroll
        for (int j = 0; j < 8; ++j) {
            int l = l0 + l16s * 16 + khalf * 8 + j;
            out[j] = (f16)src[(size_t)l * Dk + d];
        }
        size_t idx = ((((size_t)bh * 2 + db) * 128 + (l0 >> 4) + l16s) * 64 + lane) * 8;
        *(f16x8*)(vf + idx) = out;
    }
}

// ---------------- C: conv GEMM, 1024 blocks, ping-pong pipelined frag loads ----------------
// R4 swizzle (best measured): 4 oTile-siblings share id&7.
__global__ __launch_bounds__(256, 4) void kconv(
    const float* __restrict__ Q, const float* __restrict__ K, const int* __restrict__ flag,
    const f16* __restrict__ afhq, const f16* __restrict__ aflq,
    const f16* __restrict__ afhk, const f16* __restrict__ aflk,
    const f16* __restrict__ wfhq, const f16* __restrict__ wflq,
    const f16* __restrict__ wfhk, const f16* __restrict__ wflk,
    f16* __restrict__ ffhq, f16* __restrict__ fflq,
    f16* __restrict__ ffhk, f16* __restrict__ fflk) {
    int id = blockIdx.x;
    int xcd = id & 7, oTile = (id >> 3) & 3, gidx = id >> 5;
    int g = gidx * 8 + xcd;
    int tt = g & 31, b = (g >> 5) & 3, tensor = (g >> 7) & 1;
    int wave = threadIdx.x >> 6, lane = threadIdx.x & 63;
    int wn = wave & 1, wm = wave >> 1;
    int lane31 = lane & 31, khalf = lane >> 5;
    const f16* ah = (tensor ? afhk : afhq) + ((size_t)(b * 64 + tt * 2 + wm) * 128) * 512;
    const f16* al = (tensor ? aflk : aflq) + ((size_t)(b * 64 + tt * 2 + wm) * 128) * 512;
    const f16* bhp = (tensor ? wfhk : wfhq) + ((size_t)(oTile * 4 + wn * 2) * 128) * 512;
    const f16* blp = (tensor ? wflk : wflq) + ((size_t)(oTile * 4 + wn * 2) * 128) * 512;
    const float* src = (tensor ? K : Q) + (size_t)b * Hh * Ll * Dk;
    f16* dh = (tensor ? ffhk : ffhq);
    f16* dl = (tensor ? fflk : fflq);
    const float scale = tensor ? 1.f : QSCALE;
    const int klen16 = (*flag) << 5;            // 128 or 64 (even)

    f32x16 acc[2];
#pragma unroll
    for (int j = 0; j < 2; ++j)
#pragma unroll
        for (int r = 0; r < 16; ++r) acc[j][r] = 0.f;

    f16x8 Aah, Aal, Abh[2], Abl[2];             // buffer A
    f16x8 Bah, Bal, Bbh[2], Bbl[2];             // buffer B
    const size_t lo8 = (size_t)lane * 8;

    // prime buffer A with k16=0
    Aah = *(const f16x8*)(ah + lo8);
    Aal = *(const f16x8*)(al + lo8);
    Abh[0] = *(const f16x8*)(bhp + lo8);
    Abl[0] = *(const f16x8*)(blp + lo8);
    Abh[1] = *(const f16x8*)(bhp + 128 * 512 + lo8);
    Abl[1] = *(const f16x8*)(blp + 128 * 512 + lo8);

    for (int k16 = 0; k16 < klen16; k16 += 2) {
        {   // prefetch k16+1 into B
            int kn = k16 + 1 < klen16 ? k16 + 1 : k16;
            size_t o = (size_t)kn * 512 + lo8;
            Bah = *(const f16x8*)(ah + o);
            Bal = *(const f16x8*)(al + o);
            Bbh[0] = *(const f16x8*)(bhp + o);
            Bbl[0] = *(const f16x8*)(blp + o);
            Bbh[1] = *(const f16x8*)(bhp + 128 * 512 + o);
            Bbl[1] = *(const f16x8*)(blp + 128 * 512 + o);
        }
#pragma unroll
        for (int j = 0; j < 2; ++j) {
            acc[j] = MFMA32(Aah, Abh[j], acc[j]);
            acc[j] = MFMA32(Aah, Abl[j], acc[j]);
            acc[j] = MFMA32(Aal, Abh[j], acc[j]);
        }
        {   // prefetch k16+2 into A
            int kn = k16 + 2 < klen16 ? k16 + 2 : klen16 - 1;
            size_t o = (size_t)kn * 512 + lo8;
            Aah = *(const f16x8*)(ah + o);
            Aal = *(const f16x8*)(al + o);
            Abh[0] = *(const f16x8*)(bhp + o);
            Abl[0] = *(const f16x8*)(blp + o);
            Abh[1] = *(const f16x8*)(bhp + 128 * 512 + o);
            Abl[1] = *(const f16x8*)(blp + 128 * 512 + o);
        }
#pragma unroll
        for (int j = 0; j < 2; ++j) {
            acc[j] = MFMA32(Bah, Bbh[j], acc[j]);
            acc[j] = MFMA32(Bah, Bbl[j], acc[j]);
            acc[j] = MFMA32(Bal, Bbh[j], acc[j]);
        }
    }
    // epilogue: C[t][o] -> flat (h,l,d), add residual, scale, split, store in kattn frag order
#pragma unroll
    for (int j = 0; j < 2; ++j)
#pragma unroll
        for (int r = 0; r < 16; ++r) {
            int trow = tt * 64 + wm * 32 + (r & 3) + ((r >> 2) << 3) + (khalf << 2);
            int ocol = oTile * 128 + wn * 64 + j * 32 + lane31;
            int h = trow >> 8;
            int l = ((trow & 255) << 3) + (ocol >> 6);
            int d = ocol & 63;
            float v2 = (acc[j][r] + src[((size_t)h * Ll + l) * Dk + d]) * scale;
            f16 hi = (f16)v2;
            f16 lo = (f16)(v2 - (float)hi);
            size_t idx = ((((size_t)(b * 8 + h) * 64 + (l >> 5)) * 4 + (d >> 4)) * 64
                          + ((d >> 3) & 1) * 32 + (l & 31)) * 8 + (d & 7);
            dh[idx] = hi; dl[idx] = lo;
        }
}

// ---------------- F: fused attention, K-split across wave pairs ----------------
// R8 == R4 verbatim (best measured: 2 blk/CU keeps per-XCD K/V L2-resident under
// the attn write stream; 3 blk/CU thrashes -> FETCH 201MB, R7). Superstep 8,
// 1KB-per-row cached bursts, sbuf/combuf union.
#define LOADK(DST, CH) do { size_t kb_ = (size_t)(CH) * 2048 + lane * 8;            \
    _Pragma("unroll") for (int ks_ = 0; ks_ < 4; ++ks_) {                           \
        DST[2 * ks_]     = *(const f16x8*)(kbh + kb_ + ks_ * 512);                  \
        DST[2 * ks_ + 1] = *(const f16x8*)(kbl + kb_ + ks_ * 512); } } while (0)

#define QKM(SRC, ACC) do { _Pragma("unroll") for (int ks_ = 0; ks_ < 4; ++ks_) {    \
        ACC = MFMA32(a_h[ks_], SRC[2 * ks_], ACC);                                  \
        ACC = MFMA32(a_h[ks_], SRC[2 * ks_ + 1], ACC);                              \
        ACC = MFMA32(a_l[ks_], SRC[2 * ks_], ACC); } } while (0)

#define SMUPD(ACC) do { _Pragma("unroll") for (int r_ = 0; r_ < 16; ++r_) {         \
        float v_ = ACC[r_]; float d_ = v_ - m[r_]; float e_ = exp2f(-fabsf(d_));    \
        bool gt_ = d_ > 0.f;                                                        \
        s[r_] = gt_ ? __fmaf_rn(s[r_], e_, 1.f) : (s[r_] + e_);                     \
        m[r_] = gt_ ? v_ : m[r_]; } } while (0)

#define LOADV(DST, CH) do { _Pragma("unroll") for (int q_ = 0; q_ < 4; ++q_) {      \
        int n_ = q_ >> 1, ks2_ = q_ & 1;                                            \
        size_t off_ = ((((size_t)bh * 2 + n_) * 128 + (CH) * 2 + ks2_) * 64 + lane) * 8; \
        DST[q_] = *(const f16x8*)(vf + off_); } } while (0)

union SMemU {
    float combuf[2][32][64];   // 16 KB exchange buffer (softmax combine, ctx reduce)
    f16 sbuf[4][32][264];      // 66 KB P stage: 528B rows (132w % 32 == 4, same
                               // conflict-free b128 class as proven 136-row layout)
};

__global__ __launch_bounds__(256, 2) void kattn(
    const f16* __restrict__ qfh, const f16* __restrict__ qfl,
    const f16* __restrict__ kfh, const f16* __restrict__ kfl,
    const f16* __restrict__ vf,
    float* __restrict__ ctx_out, float* __restrict__ attn_out) {
    __shared__ __align__(16) SMemU sm;
    int id = blockIdx.x;                              // 1024; 4 bh per XCD for K/V L2 locality
    int bh = (id & 7) * 4 + (id >> 8);
    int qt = (id >> 3) & 31;
    int wave = threadIdx.x >> 6, lane = threadIdx.x & 63;
    int qg = wave >> 1, kg = wave & 1;
    int lane31 = lane & 31, khalf = lane >> 5;
    int q0 = qt * 64 + qg * 32;

    // resident Q fragments (hi/lo): 4 ksteps of 16 over d_k=64, contiguous 1KB loads
    f16x8 a_h[4], a_l[4];
    {
        size_t qb = ((size_t)bh * 64 + qt * 2 + qg) * 4;
#pragma unroll
        for (int ks = 0; ks < 4; ++ks) {
            a_h[ks] = *(const f16x8*)(qfh + ((qb + ks) * 64 + lane) * 8);
            a_l[ks] = *(const f16x8*)(qfl + ((qb + ks) * 64 + lane) * 8);
        }
    }
    const f16* kbh = kfh + (size_t)bh * 131072;
    const f16* kbl = kfl + (size_t)bh * 131072;
    const int ch0 = kg * 32, ch1 = ch0 + 32;

    float m[16], s[16];
#pragma unroll
    for (int r = 0; r < 16; ++r) { m[r] = -3.0e38f; s[r] = 0.f; }

    // ---- pass 1: online row max + sum of 2^z, K register ping-pong ----
    {
        f16x8 KA[8], KB[8];
        LOADK(KA, ch0);
        for (int ch = ch0; ch < ch1; ch += 2) {
            LOADK(KB, ch + 1);
            f32x16 acc;
#pragma unroll
            for (int r = 0; r < 16; ++r) acc[r] = 0.f;
            QKM(KA, acc);
            SMUPD(acc);
            {
                int chn = (ch + 2 < ch1) ? ch + 2 : ch;
                LOADK(KA, chn);
            }
            f32x16 acc2;
#pragma unroll
            for (int r = 0; r < 16; ++r) acc2[r] = 0.f;
            QKM(KB, acc2);
            SMUPD(acc2);
        }
    }
    // lane combine within the 32 col-lanes of each half
#pragma unroll
    for (int r = 0; r < 16; ++r) {
        float mm = m[r], ss = s[r];
#pragma unroll
        for (int off = 1; off < 32; off <<= 1) {
            float mo = __shfl_xor(mm, off, 64);
            float so = __shfl_xor(ss, off, 64);
            float mn = fmaxf(mm, mo);
            ss = ss * exp2f(mm - mn) + so * exp2f(mo - mn);
            mm = mn;
        }
        m[r] = mm; s[r] = ss;
    }
    // cross-wave (k-split) combine through LDS
    if (kg == 1) {
#pragma unroll
        for (int r = 0; r < 16; ++r) {
            sm.combuf[qg][r][lane] = m[r];
            sm.combuf[qg][16 + r][lane] = s[r];
        }
    }
    __syncthreads();
    if (kg == 0) {
#pragma unroll
        for (int r = 0; r < 16; ++r) {
            float m1 = sm.combuf[qg][r][lane];
            float s1 = sm.combuf[qg][16 + r][lane];
            float mn = fmaxf(m[r], m1);
            float ss = s[r] * exp2f(m[r] - mn) + s1 * exp2f(m1 - mn);
            m[r] = mn; s[r] = 1.f / ss;
            sm.combuf[qg][r][lane] = mn;
            sm.combuf[qg][16 + r][lane] = s[r];
        }
    }
    __syncthreads();
    if (kg == 1) {
#pragma unroll
        for (int r = 0; r < 16; ++r) {
            m[r] = sm.combuf[qg][r][lane];
            s[r] = sm.combuf[qg][16 + r][lane];
        }
    }
    __syncthreads();   // union hazard: combuf reads must finish before sbuf writes

    f32x16 ctx[2];
#pragma unroll
    for (int n = 0; n < 2; ++n)
#pragma unroll
        for (int r = 0; r < 16; ++r) ctx[n][r] = 0.f;

    const size_t rowbase = ((size_t)bh * Ll + q0) * Ll;

    // ---- pass 2: recompute scores (identical op order), stage P in LDS, PV,
    //      then sweep 256-col batches to attn_out as 1KB-per-row bursts ----
    {
        f16x8 KV[8], VV[4];
        LOADK(KV, ch0);
        LOADV(VV, ch0);
        for (int chb = ch0; chb < ch1; chb += 8) {
#pragma unroll
            for (int i = 0; i < 8; ++i) {
                int ch = chb + i;
                f32x16 acc;
#pragma unroll
                for (int r = 0; r < 16; ++r) acc[r] = 0.f;
                QKM(KV, acc);
                int chn = (ch + 1 < ch1) ? ch + 1 : ch;
                LOADK(KV, chn);              // WAR on KV: safe after MFMA issue; covered by tail
#pragma unroll
                for (int r = 0; r < 16; ++r) {
                    float p = exp2f(acc[r] - m[r]) * s[r];
                    int row = (r & 3) + ((r >> 2) << 3) + (khalf << 2);
                    sm.sbuf[wave][row][i * 32 + lane31] = (f16)p;
                }
                __asm__ volatile("s_waitcnt lgkmcnt(0)" ::: "memory");  // wave-private LDS RAW
#pragma unroll
                for (int ks2 = 0; ks2 < 2; ++ks2) {
                    f16x8 pa = *(const f16x8*)&sm.sbuf[wave][lane31][i * 32 + ks2 * 16 + khalf * 8];
                    ctx[0] = MFMA32(pa, VV[ks2], ctx[0]);
                    ctx[1] = MFMA32(pa, VV[2 + ks2], ctx[1]);
                }
                LOADV(VV, chn);              // covered by next QK cluster
            }
            // store sweep: 32 rows x 256 cols, 1KB contiguous per row, cached stores
#pragma unroll
            for (int ri = 0; ri < 16; ++ri) {
                int row = ri * 2 + khalf;
                f16x8 pv = *(const f16x8*)&sm.sbuf[wave][row][lane31 * 8];
                f32x4 o0 = {(float)pv[0], (float)pv[1], (float)pv[2], (float)pv[3]};
                f32x4 o1 = {(float)pv[4], (float)pv[5], (float)pv[6], (float)pv[7]};
                float* dst = attn_out + rowbase + (size_t)row * Ll + chb * 32 + lane31 * 8;
                *(f32x4*)dst = o0;
                *(f32x4*)(dst + 4) = o1;
            }
        }
    }
    // ---- k-split ctx reduction ----
    __syncthreads();
    if (kg == 1) {
#pragma unroll
        for (int n = 0; n < 2; ++n)
#pragma unroll
            for (int r = 0; r < 16; ++r) sm.combuf[qg][n * 16 + r][lane] = ctx[n][r];
    }
    __syncthreads();
    if (kg == 0) {
#pragma unroll
        for (int n = 0; n < 2; ++n)
#pragma unroll
            for (int r = 0; r < 16; ++r) {
                float v = ctx[n][r] + sm.combuf[qg][n * 16 + r][lane];
                int row = (r & 3) + ((r >> 2) << 3) + (khalf << 2);
                ctx_out[((size_t)bh * Ll + q0 + row) * Dk + n * 32 + lane31] = v;
            }
    }
}

extern "C" void kernel_launch(void* const* d_in, const int* in_sizes, int n_in,
                              void* d_out, int out_size, void* d_ws, size_t ws_size,
                              hipStream_t stream) {
    const float* Q = (const float*)d_in[0];
    const float* K = (const float*)d_in[1];
    const float* V = (const float*)d_in[2];
    // d_in[3] = attn_mask (all-false, unused)
    const float* convq = (const float*)d_in[4];
    const float* convk = (const float*)d_in[5];
    const float* w = (const float*)d_in[6];

    char* ws = (char*)d_ws;
    int* flag = (int*)ws;
    f16* wfhq = (f16*)(ws + OFF_WF);
    f16* wflq = wfhq + NWF;
    f16* wfhk = wflq + NWF;
    f16* wflk = wfhk + NWF;
    f16* afhq = (f16*)(ws + OFF_AF);
    f16* aflq = afhq + NAF;
    f16* afhk = aflq + NAF;
    f16* aflk = afhk + NAF;
    f16* ffhq = (f16*)(ws + OFF_FF);
    f16* fflq = ffhq + NFF;
    f16* ffhk = fflq + NFF;
    f16* fflk = ffhk + NFF;
    f16* vf = (f16*)(ws + OFF_VF);

    float* ctx_out = (float*)d_out;
    float* attn_out = ctx_out + (size_t)BH * Ll * Dk;

    kprep_w<<<dim3(128, 2), 256, 0, stream>>>(convq, convk, w, flag, wfhq, wflq, wfhk, wflk);
    kprep_v<<<dim3(16, 32), 256, 0, stream>>>(V, vf);
    kprep_a<<<dim3(512, 4, 2), 256, 0, stream>>>(Q, K, flag, afhq, aflq, afhk, aflk);
    kconv<<<dim3(1024), 256, 0, stream>>>(Q, K, flag, afhq, aflq, afhk, aflk,
                                          wfhq, wflq, wfhk, wflk, ffhq, fflq, ffhk, fflk);
    kattn<<<dim3(1024), 256, 0, stream>>>(ffhq, fflq, ffhk, fflk, vf, ctx_out, attn_out);
}

// Round 9
// 973.858 us; speedup vs baseline: 1.3901x; 1.0206x over previous
//
#include <hip/hip_runtime.h>

typedef _Float16 f16;
typedef _Float16 f16x4 __attribute__((ext_vector_type(4)));
typedef _Float16 f16x8 __attribute__((ext_vector_type(8)));
typedef float f32x4 __attribute__((ext_vector_type(4)));
typedef float f32x16 __attribute__((ext_vector_type(16)));

#define MFMA32(A, B, C) __builtin_amdgcn_mfma_f32_32x32x16_f16(A, B, C, 0, 0, 0)

constexpr int Bb = 4, Hh = 8, Ll = 2048, Dk = 64, Dm = 512, BH = 32;

// element counts per (tensor,hilo) array
constexpr size_t NWF = (size_t)16 * 128 * 64 * 8;      // W frag: [ob16][k16:128][lane][8]
constexpr size_t NFF = (size_t)BH * 64 * 4 * 64 * 8;   // Qc/Kc frag: [bh][lb64][d16:4][lane][8]
constexpr size_t NVF = (size_t)BH * 2 * 128 * 64 * 8;  // V frag: [bh][db2][l16:128][lane][8]

constexpr size_t OFF_WF = 256;
constexpr size_t OFF_FF = OFF_WF + 4 * NWF * sizeof(f16);
constexpr size_t OFF_VF = OFF_FF + 4 * NFF * sizeof(f16);

// scores computed in base-2: fold log2(e)/sqrt(64) into Qc (exact softmax identity)
#define QSCALE 0.1803368801111204f

// ---------------- P1: mask + split conv weights into frag order ----------------
// R8: thread owns 8 consecutive c for one o -> contiguous 16B writes.
__global__ void kprep_w(const float* __restrict__ convq, const float* __restrict__ convk,
                        const float* __restrict__ w, int* __restrict__ flag,
                        f16* __restrict__ wfhq, f16* __restrict__ wflq,
                        f16* __restrict__ wfhk, f16* __restrict__ wflk) {
    const int len = (4.f * w[1] > 2.f * w[0]) ? 4 : 2;   // argmax([2w0,4w1]) -> FILTER_LENGTHS[ind]
    if (blockIdx.x == 0 && blockIdx.y == 0 && threadIdx.x == 0) *flag = len;
    int g = blockIdx.x * 256 + threadIdx.x;              // [0,32768) = c8*512 + o
    int o = g & 511, c8 = g >> 9;                        // c = c8*8 + cc
    const float* conv = blockIdx.y ? convk : convq;
    f16* dh = blockIdx.y ? wfhk : wfhq;
    f16* dl = blockIdx.y ? wflk : wflq;
    float4 v[8];
#pragma unroll
    for (int cc = 0; cc < 8; ++cc)                       // coalesced: lanes read consecutive float4
        v[cc] = *(const float4*)(conv + ((size_t)(c8 * 8 + cc) * 512 + o) * 4);
    int ob = o >> 5;
#pragma unroll
    for (int f = 0; f < 4; ++f) {
        f16x8 hv, lv;
#pragma unroll
        for (int cc = 0; cc < 8; ++cc) {
            float x = (f < len) ? ((const float*)&v[cc])[f] : 0.f;
            f16 hi = (f16)x;
            hv[cc] = hi; lv[cc] = (f16)(x - (float)hi);
        }
        // k = f*512 + c8*8 + cc: k&7=cc, (k>>3)&1=c8&1, k16=f*32+(c8>>1)
        int k16 = f * 32 + (c8 >> 1);
        size_t base = (((size_t)ob * 128 + k16) * 64 + (c8 & 1) * 32 + (o & 31)) * 8;
        *(f16x8*)(dh + base) = hv;
        *(f16x8*)(dl + base) = lv;
    }
}

// ---------------- P3: V -> frag order for PV B-operand ----------------
__global__ void kprep_v(const float* __restrict__ V, f16* __restrict__ vf) {
    int bh = blockIdx.y, l0 = blockIdx.x * 128;
    int tid = threadIdx.x;
    const float* src = V + (size_t)bh * Ll * Dk;
#pragma unroll
    for (int s = 0; s < 4; ++s) {
        int g = s * 4 + (tid >> 6);
        int lane = tid & 63;
        int l16s = g >> 1, db = g & 1;
        int khalf = lane >> 5, lane31 = lane & 31;
        int d = db * 32 + lane31;
        f16x8 out;
#pragma unroll
        for (int j = 0; j < 8; ++j) {
            int l = l0 + l16s * 16 + khalf * 8 + j;
            out[j] = (f16)src[(size_t)l * Dk + d];
        }
        size_t idx = ((((size_t)bh * 2 + db) * 128 + (l0 >> 4) + l16s) * 64 + lane) * 8;
        *(f16x8*)(vf + idx) = out;
    }
}

// ---------------- C: conv GEMM with FUSED A-operand construction ----------------
// R9: kprep_a deleted. A-fragments are built on the fly from Q/K: per k16, lane
// (khalf,lane31) needs S[cb+j][t0-2+lane31+f] (8 row-strided loads, lanes 0-31
// contiguous 128B runs), then hi/lo split in registers. Saves the 134MB A-frag
// write + 134MB re-read; S (33.5MB) is L3-resident and L2-hot (4 oTile siblings
// per XCD read identical octets). Boundary via clamp + 0/1-mask multiply
// (bit-identical to kprep_a's zero-padded tile). W ping-pong + epilogue unchanged.
__global__ __launch_bounds__(256, 4) void kconv(
    const float* __restrict__ Q, const float* __restrict__ K, const int* __restrict__ flag,
    const f16* __restrict__ wfhq, const f16* __restrict__ wflq,
    const f16* __restrict__ wfhk, const f16* __restrict__ wflk,
    f16* __restrict__ ffhq, f16* __restrict__ fflq,
    f16* __restrict__ ffhk, f16* __restrict__ fflk) {
    int id = blockIdx.x;                        // R4 swizzle: 4 oTile-siblings share id&7
    int xcd = id & 7, oTile = (id >> 3) & 3, gidx = id >> 5;
    int g = gidx * 8 + xcd;
    int tt = g & 31, b = (g >> 5) & 3, tensor = (g >> 7) & 1;
    int wave = threadIdx.x >> 6, lane = threadIdx.x & 63;
    int wn = wave & 1, wm = wave >> 1;
    int lane31 = lane & 31, khalf = lane >> 5;
    const f16* bhp = (tensor ? wfhk : wfhq) + ((size_t)(oTile * 4 + wn * 2) * 128) * 512;
    const f16* blp = (tensor ? wflk : wflq) + ((size_t)(oTile * 4 + wn * 2) * 128) * 512;
    const float* src = (tensor ? K : Q) + (size_t)b * Dm * Ll;  // flat [512][2048] view
    f16* dh = (tensor ? ffhk : ffhq);
    f16* dl = (tensor ? fflk : fflq);
    const float scale = tensor ? 1.f : QSCALE;
    const int klen16 = (*flag) << 5;            // 128 or 64 (even)
    const int t0 = (tt * 2 + wm) * 32;
    const int coff = khalf * 8;

    f32x16 acc[2];
#pragma unroll
    for (int j = 0; j < 2; ++j)
#pragma unroll
        for (int r = 0; r < 16; ++r) acc[j][r] = 0.f;

    f16x8 Abh[2], Abl[2], Bbh[2], Bbl[2];       // W ping-pong buffers
    float XA[8], XB[8], mkA, mkB;               // A-source octet ping-pong (f32)
    const size_t lo8 = (size_t)lane * 8;

// load the 8-float S octet for k16=KN into X[], boundary mask into MK
#define LOADX(X, MK, KN) do {                                                        \
    int f_ = (KN) >> 5;                                                              \
    int cb_ = (((KN) >> 2) & 7) * 64 + ((KN) & 3) * 16 + coff;                       \
    int t_ = t0 - 2 + lane31 + f_;                                                   \
    int tc_ = t_ < 0 ? 0 : (t_ > Ll - 1 ? Ll - 1 : t_);                              \
    MK = (t_ == tc_) ? 1.f : 0.f;                                                    \
    const float* sp_ = src + (size_t)cb_ * Ll + tc_;                                 \
    _Pragma("unroll") for (int j_ = 0; j_ < 8; ++j_) X[j_] = sp_[(size_t)j_ * Ll];   \
} while (0)

// convert masked f32 octet to hi/lo f16x8 fragments
#define CVTA(X, MK, AH, AL) do {                                                     \
    _Pragma("unroll") for (int j_ = 0; j_ < 8; ++j_) {                               \
        float x_ = X[j_] * MK; f16 h_ = (f16)x_;                                     \
        AH[j_] = h_; AL[j_] = (f16)(x_ - (float)h_); }                               \
} while (0)

    // prime buffer A with k16=0
    LOADX(XA, mkA, 0);
    Abh[0] = *(const f16x8*)(bhp + lo8);
    Abl[0] = *(const f16x8*)(blp + lo8);
    Abh[1] = *(const f16x8*)(bhp + 128 * 512 + lo8);
    Abl[1] = *(const f16x8*)(blp + 128 * 512 + lo8);

    for (int k16 = 0; k16 < klen16; k16 += 2) {
        {   // prefetch k16+1 into B
            int kn = k16 + 1;
            LOADX(XB, mkB, kn);
            size_t o = (size_t)kn * 512 + lo8;
            Bbh[0] = *(const f16x8*)(bhp + o);
            Bbl[0] = *(const f16x8*)(blp + o);
            Bbh[1] = *(const f16x8*)(bhp + 128 * 512 + o);
            Bbl[1] = *(const f16x8*)(blp + 128 * 512 + o);
        }
        {
            f16x8 Ah, Al;
            CVTA(XA, mkA, Ah, Al);
#pragma unroll
            for (int j = 0; j < 2; ++j) {
                acc[j] = MFMA32(Ah, Abh[j], acc[j]);
                acc[j] = MFMA32(Ah, Abl[j], acc[j]);
                acc[j] = MFMA32(Al, Abh[j], acc[j]);
            }
        }
        {   // prefetch k16+2 into A
            int kn = k16 + 2 < klen16 ? k16 + 2 : klen16 - 1;
            LOADX(XA, mkA, kn);
            size_t o = (size_t)kn * 512 + lo8;
            Abh[0] = *(const f16x8*)(bhp + o);
            Abl[0] = *(const f16x8*)(blp + o);
            Abh[1] = *(const f16x8*)(bhp + 128 * 512 + o);
            Abl[1] = *(const f16x8*)(blp + 128 * 512 + o);
        }
        {
            f16x8 Bh, Bl;
            CVTA(XB, mkB, Bh, Bl);
#pragma unroll
            for (int j = 0; j < 2; ++j) {
                acc[j] = MFMA32(Bh, Bbh[j], acc[j]);
                acc[j] = MFMA32(Bh, Bbl[j], acc[j]);
                acc[j] = MFMA32(Bl, Bbh[j], acc[j]);
            }
        }
    }
#undef LOADX
#undef CVTA
    // epilogue: C[t][o] -> flat (h,l,d), add residual, scale, split, store in kattn frag order
#pragma unroll
    for (int j = 0; j < 2; ++j)
#pragma unroll
        for (int r = 0; r < 16; ++r) {
            int trow = tt * 64 + wm * 32 + (r & 3) + ((r >> 2) << 3) + (khalf << 2);
            int ocol = oTile * 128 + wn * 64 + j * 32 + lane31;
            int h = trow >> 8;
            int l = ((trow & 255) << 3) + (ocol >> 6);
            int d = ocol & 63;
            float v2 = (acc[j][r] + src[((size_t)h * Ll + l) * Dk + d]) * scale;
            f16 hi = (f16)v2;
            f16 lo = (f16)(v2 - (float)hi);
            size_t idx = ((((size_t)(b * 8 + h) * 64 + (l >> 5)) * 4 + (d >> 4)) * 64
                          + ((d >> 3) & 1) * 32 + (l & 31)) * 8 + (d & 7);
            dh[idx] = hi; dl[idx] = lo;
        }
}

// ---------------- F: fused attention, K-split across wave pairs ----------------
// R4 config (best measured): 2 blk/CU, superstep 8, 1KB-per-row cached bursts,
// sbuf/combuf union.
#define LOADK(DST, CH) do { size_t kb_ = (size_t)(CH) * 2048 + lane * 8;            \
    _Pragma("unroll") for (int ks_ = 0; ks_ < 4; ++ks_) {                           \
        DST[2 * ks_]     = *(const f16x8*)(kbh + kb_ + ks_ * 512);                  \
        DST[2 * ks_ + 1] = *(const f16x8*)(kbl + kb_ + ks_ * 512); } } while (0)

#define QKM(SRC, ACC) do { _Pragma("unroll") for (int ks_ = 0; ks_ < 4; ++ks_) {    \
        ACC = MFMA32(a_h[ks_], SRC[2 * ks_], ACC);                                  \
        ACC = MFMA32(a_h[ks_], SRC[2 * ks_ + 1], ACC);                              \
        ACC = MFMA32(a_l[ks_], SRC[2 * ks_], ACC); } } while (0)

#define SMUPD(ACC) do { _Pragma("unroll") for (int r_ = 0; r_ < 16; ++r_) {         \
        float v_ = ACC[r_]; float d_ = v_ - m[r_]; float e_ = exp2f(-fabsf(d_));    \
        bool gt_ = d_ > 0.f;                                                        \
        s[r_] = gt_ ? __fmaf_rn(s[r_], e_, 1.f) : (s[r_] + e_);                     \
        m[r_] = gt_ ? v_ : m[r_]; } } while (0)

#define LOADV(DST, CH) do { _Pragma("unroll") for (int q_ = 0; q_ < 4; ++q_) {      \
        int n_ = q_ >> 1, ks2_ = q_ & 1;                                            \
        size_t off_ = ((((size_t)bh * 2 + n_) * 128 + (CH) * 2 + ks2_) * 64 + lane) * 8; \
        DST[q_] = *(const f16x8*)(vf + off_); } } while (0)

union SMemU {
    float combuf[2][32][64];   // 16 KB exchange buffer (softmax combine, ctx reduce)
    f16 sbuf[4][32][264];      // 66 KB P stage: 528B rows (132w % 32 == 4, same
                               // conflict-free b128 class as proven 136-row layout)
};

__global__ __launch_bounds__(256, 2) void kattn(
    const f16* __restrict__ qfh, const f16* __restrict__ qfl,
    const f16* __restrict__ kfh, const f16* __restrict__ kfl,
    const f16* __restrict__ vf,
    float* __restrict__ ctx_out, float* __restrict__ attn_out) {
    __shared__ __align__(16) SMemU sm;
    int id = blockIdx.x;                              // 1024; 4 bh per XCD for K/V L2 locality
    int bh = (id & 7) * 4 + (id >> 8);
    int qt = (id >> 3) & 31;
    int wave = threadIdx.x >> 6, lane = threadIdx.x & 63;
    int qg = wave >> 1, kg = wave & 1;
    int lane31 = lane & 31, khalf = lane >> 5;
    int q0 = qt * 64 + qg * 32;

    // resident Q fragments (hi/lo): 4 ksteps of 16 over d_k=64, contiguous 1KB loads
    f16x8 a_h[4], a_l[4];
    {
        size_t qb = ((size_t)bh * 64 + qt * 2 + qg) * 4;
#pragma unroll
        for (int ks = 0; ks < 4; ++ks) {
            a_h[ks] = *(const f16x8*)(qfh + ((qb + ks) * 64 + lane) * 8);
            a_l[ks] = *(const f16x8*)(qfl + ((qb + ks) * 64 + lane) * 8);
        }
    }
    const f16* kbh = kfh + (size_t)bh * 131072;
    const f16* kbl = kfl + (size_t)bh * 131072;
    const int ch0 = kg * 32, ch1 = ch0 + 32;

    float m[16], s[16];
#pragma unroll
    for (int r = 0; r < 16; ++r) { m[r] = -3.0e38f; s[r] = 0.f; }

    // ---- pass 1: online row max + sum of 2^z, K register ping-pong ----
    {
        f16x8 KA[8], KB[8];
        LOADK(KA, ch0);
        for (int ch = ch0; ch < ch1; ch += 2) {
            LOADK(KB, ch + 1);
            f32x16 acc;
#pragma unroll
            for (int r = 0; r < 16; ++r) acc[r] = 0.f;
            QKM(KA, acc);
            SMUPD(acc);
            {
                int chn = (ch + 2 < ch1) ? ch + 2 : ch;
                LOADK(KA, chn);
            }
            f32x16 acc2;
#pragma unroll
            for (int r = 0; r < 16; ++r) acc2[r] = 0.f;
            QKM(KB, acc2);
            SMUPD(acc2);
        }
    }
    // lane combine within the 32 col-lanes of each half
#pragma unroll
    for (int r = 0; r < 16; ++r) {
        float mm = m[r], ss = s[r];
#pragma unroll
        for (int off = 1; off < 32; off <<= 1) {
            float mo = __shfl_xor(mm, off, 64);
            float so = __shfl_xor(ss, off, 64);
            float mn = fmaxf(mm, mo);
            ss = ss * exp2f(mm - mn) + so * exp2f(mo - mn);
            mm = mn;
        }
        m[r] = mm; s[r] = ss;
    }
    // cross-wave (k-split) combine through LDS
    if (kg == 1) {
#pragma unroll
        for (int r = 0; r < 16; ++r) {
            sm.combuf[qg][r][lane] = m[r];
            sm.combuf[qg][16 + r][lane] = s[r];
        }
    }
    __syncthreads();
    if (kg == 0) {
#pragma unroll
        for (int r = 0; r < 16; ++r) {
            float m1 = sm.combuf[qg][r][lane];
            float s1 = sm.combuf[qg][16 + r][lane];
            float mn = fmaxf(m[r], m1);
            float ss = s[r] * exp2f(m[r] - mn) + s1 * exp2f(m1 - mn);
            m[r] = mn; s[r] = 1.f / ss;
            sm.combuf[qg][r][lane] = mn;
            sm.combuf[qg][16 + r][lane] = s[r];
        }
    }
    __syncthreads();
    if (kg == 1) {
#pragma unroll
        for (int r = 0; r < 16; ++r) {
            m[r] = sm.combuf[qg][r][lane];
            s[r] = sm.combuf[qg][16 + r][lane];
        }
    }
    __syncthreads();   // union hazard: combuf reads must finish before sbuf writes

    f32x16 ctx[2];
#pragma unroll
    for (int n = 0; n < 2; ++n)
#pragma unroll
        for (int r = 0; r < 16; ++r) ctx[n][r] = 0.f;

    const size_t rowbase = ((size_t)bh * Ll + q0) * Ll;

    // ---- pass 2: recompute scores (identical op order), stage P in LDS, PV,
    //      then sweep 256-col batches to attn_out as 1KB-per-row bursts ----
    {
        f16x8 KV[8], VV[4];
        LOADK(KV, ch0);
        LOADV(VV, ch0);
        for (int chb = ch0; chb < ch1; chb += 8) {
#pragma unroll
            for (int i = 0; i < 8; ++i) {
                int ch = chb + i;
                f32x16 acc;
#pragma unroll
                for (int r = 0; r < 16; ++r) acc[r] = 0.f;
                QKM(KV, acc);
                int chn = (ch + 1 < ch1) ? ch + 1 : ch;
                LOADK(KV, chn);              // WAR on KV: safe after MFMA issue; covered by tail
#pragma unroll
                for (int r = 0; r < 16; ++r) {
                    float p = exp2f(acc[r] - m[r]) * s[r];
                    int row = (r & 3) + ((r >> 2) << 3) + (khalf << 2);
                    sm.sbuf[wave][row][i * 32 + lane31] = (f16)p;
                }
                __asm__ volatile("s_waitcnt lgkmcnt(0)" ::: "memory");  // wave-private LDS RAW
#pragma unroll
                for (int ks2 = 0; ks2 < 2; ++ks2) {
                    f16x8 pa = *(const f16x8*)&sm.sbuf[wave][lane31][i * 32 + ks2 * 16 + khalf * 8];
                    ctx[0] = MFMA32(pa, VV[ks2], ctx[0]);
                    ctx[1] = MFMA32(pa, VV[2 + ks2], ctx[1]);
                }
                LOADV(VV, chn);              // covered by next QK cluster
            }
            // store sweep: 32 rows x 256 cols, 1KB contiguous per row, cached stores
#pragma unroll
            for (int ri = 0; ri < 16; ++ri) {
                int row = ri * 2 + khalf;
                f16x8 pv = *(const f16x8*)&sm.sbuf[wave][row][lane31 * 8];
                f32x4 o0 = {(float)pv[0], (float)pv[1], (float)pv[2], (float)pv[3]};
                f32x4 o1 = {(float)pv[4], (float)pv[5], (float)pv[6], (float)pv[7]};
                float* dst = attn_out + rowbase + (size_t)row * Ll + chb * 32 + lane31 * 8;
                *(f32x4*)dst = o0;
                *(f32x4*)(dst + 4) = o1;
            }
        }
    }
    // ---- k-split ctx reduction ----
    __syncthreads();
    if (kg == 1) {
#pragma unroll
        for (int n = 0; n < 2; ++n)
#pragma unroll
            for (int r = 0; r < 16; ++r) sm.combuf[qg][n * 16 + r][lane] = ctx[n][r];
    }
    __syncthreads();
    if (kg == 0) {
#pragma unroll
        for (int n = 0; n < 2; ++n)
#pragma unroll
            for (int r = 0; r < 16; ++r) {
                float v = ctx[n][r] + sm.combuf[qg][n * 16 + r][lane];
                int row = (r & 3) + ((r >> 2) << 3) + (khalf << 2);
                ctx_out[((size_t)bh * Ll + q0 + row) * Dk + n * 32 + lane31] = v;
            }
    }
}

extern "C" void kernel_launch(void* const* d_in, const int* in_sizes, int n_in,
                              void* d_out, int out_size, void* d_ws, size_t ws_size,
                              hipStream_t stream) {
    const float* Q = (const float*)d_in[0];
    const float* K = (const float*)d_in[1];
    const float* V = (const float*)d_in[2];
    // d_in[3] = attn_mask (all-false, unused)
    const float* convq = (const float*)d_in[4];
    const float* convk = (const float*)d_in[5];
    const float* w = (const float*)d_in[6];

    char* ws = (char*)d_ws;
    int* flag = (int*)ws;
    f16* wfhq = (f16*)(ws + OFF_WF);
    f16* wflq = wfhq + NWF;
    f16* wfhk = wflq + NWF;
    f16* wflk = wfhk + NWF;
    f16* ffhq = (f16*)(ws + OFF_FF);
    f16* fflq = ffhq + NFF;
    f16* ffhk = fflq + NFF;
    f16* fflk = ffhk + NFF;
    f16* vf = (f16*)(ws + OFF_VF);

    float* ctx_out = (float*)d_out;
    float* attn_out = ctx_out + (size_t)BH * Ll * Dk;

    kprep_w<<<dim3(128, 2), 256, 0, stream>>>(convq, convk, w, flag, wfhq, wflq, wfhk, wflk);
    kprep_v<<<dim3(16, 32), 256, 0, stream>>>(V, vf);
    kconv<<<dim3(1024), 256, 0, stream>>>(Q, K, flag,
                                          wfhq, wflq, wfhk, wflk, ffhq, fflq, ffhk, fflk);
    kattn<<<dim3(1024), 256, 0, stream>>>(ffhq, fflq, ffhk, fflk, vf, ctx_out, attn_out);
}

// Round 10
// 965.689 us; speedup vs baseline: 1.4019x; 1.0085x over previous
//
#include <hip/hip_runtime.h>

typedef _Float16 f16;
typedef _Float16 f16x4 __attribute__((ext_vector_type(4)));
typedef _Float16 f16x8 __attribute__((ext_vector_type(8)));
typedef float f32x4 __attribute__((ext_vector_type(4)));
typedef float f32x16 __attribute__((ext_vector_type(16)));

#define MFMA32(A, B, C) __builtin_amdgcn_mfma_f32_32x32x16_f16(A, B, C, 0, 0, 0)

constexpr int Bb = 4, Hh = 8, Ll = 2048, Dk = 64, Dm = 512, BH = 32;

// element counts per (tensor,hilo) array
constexpr size_t NWF = (size_t)16 * 128 * 64 * 8;      // W frag: [ob16][k16:128][lane][8]
constexpr size_t NFF = (size_t)BH * 64 * 4 * 64 * 8;   // Qc/Kc frag: [bh][lb64][d16:4][lane][8]
constexpr size_t NVF = (size_t)BH * 2 * 128 * 64 * 8;  // V frag: [bh][db2][l16:128][lane][8]

constexpr size_t OFF_WF = 256;
constexpr size_t OFF_FF = OFF_WF + 4 * NWF * sizeof(f16);
constexpr size_t OFF_VF = OFF_FF + 4 * NFF * sizeof(f16);

// scores computed in base-2: fold log2(e)/sqrt(64) into Qc (exact softmax identity)
#define QSCALE 0.1803368801111204f

// ---------------- P1: mask + split conv weights into frag order ----------------
__global__ void kprep_w(const float* __restrict__ convq, const float* __restrict__ convk,
                        const float* __restrict__ w, int* __restrict__ flag,
                        f16* __restrict__ wfhq, f16* __restrict__ wflq,
                        f16* __restrict__ wfhk, f16* __restrict__ wflk) {
    const int len = (4.f * w[1] > 2.f * w[0]) ? 4 : 2;   // argmax([2w0,4w1]) -> FILTER_LENGTHS[ind]
    if (blockIdx.x == 0 && blockIdx.y == 0 && threadIdx.x == 0) *flag = len;
    int g = blockIdx.x * 256 + threadIdx.x;              // [0,32768) = c8*512 + o
    int o = g & 511, c8 = g >> 9;                        // c = c8*8 + cc
    const float* conv = blockIdx.y ? convk : convq;
    f16* dh = blockIdx.y ? wfhk : wfhq;
    f16* dl = blockIdx.y ? wflk : wflq;
    float4 v[8];
#pragma unroll
    for (int cc = 0; cc < 8; ++cc)                       // coalesced: lanes read consecutive float4
        v[cc] = *(const float4*)(conv + ((size_t)(c8 * 8 + cc) * 512 + o) * 4);
    int ob = o >> 5;
#pragma unroll
    for (int f = 0; f < 4; ++f) {
        f16x8 hv, lv;
#pragma unroll
        for (int cc = 0; cc < 8; ++cc) {
            float x = (f < len) ? ((const float*)&v[cc])[f] : 0.f;
            f16 hi = (f16)x;
            hv[cc] = hi; lv[cc] = (f16)(x - (float)hi);
        }
        // k = f*512 + c8*8 + cc: k&7=cc, (k>>3)&1=c8&1, k16=f*32+(c8>>1)
        int k16 = f * 32 + (c8 >> 1);
        size_t base = (((size_t)ob * 128 + k16) * 64 + (c8 & 1) * 32 + (o & 31)) * 8;
        *(f16x8*)(dh + base) = hv;
        *(f16x8*)(dl + base) = lv;
    }
}

// ---------------- P3: V -> frag order for PV B-operand ----------------
__global__ void kprep_v(const float* __restrict__ V, f16* __restrict__ vf) {
    int bh = blockIdx.y, l0 = blockIdx.x * 128;
    int tid = threadIdx.x;
    const float* src = V + (size_t)bh * Ll * Dk;
#pragma unroll
    for (int s = 0; s < 4; ++s) {
        int g = s * 4 + (tid >> 6);
        int lane = tid & 63;
        int l16s = g >> 1, db = g & 1;
        int khalf = lane >> 5, lane31 = lane & 31;
        int d = db * 32 + lane31;
        f16x8 out;
#pragma unroll
        for (int j = 0; j < 8; ++j) {
            int l = l0 + l16s * 16 + khalf * 8 + j;
            out[j] = (f16)src[(size_t)l * Dk + d];
        }
        size_t idx = ((((size_t)bh * 2 + db) * 128 + (l0 >> 4) + l16s) * 64 + lane) * 8;
        *(f16x8*)(vf + idx) = out;
    }
}

// ---------------- C: conv GEMM, fused A-operand + LDS-transposed epilogue ----------------
// R10: epilogue staged through LDS. Old: 128 scalar 2B stores/thread (64-lane
// scatter over 8x16B chunks in 4KB -> segment-splitting, same disease R8 cured
// in kprep_w). New: wave's 32x64 C tile (one (h,l) per t-row, full d range) is
// hi/lo-split into est[wave][2][32][40] (80B rows, proven conflict-free class),
// then each lane stores one f16x8 (8 consecutive d of one row) = 8 x 16B
// stores/thread. Residual reads stay 128B-coalesced. Wave-private -> lgkmcnt only.
__global__ __launch_bounds__(256, 4) void kconv(
    const float* __restrict__ Q, const float* __restrict__ K, const int* __restrict__ flag,
    const f16* __restrict__ wfhq, const f16* __restrict__ wflq,
    const f16* __restrict__ wfhk, const f16* __restrict__ wflk,
    f16* __restrict__ ffhq, f16* __restrict__ fflq,
    f16* __restrict__ ffhk, f16* __restrict__ fflk) {
    __shared__ __align__(16) f16 est[4][2][32][40];   // 20.5 KB
    int id = blockIdx.x;                        // R4 swizzle: 4 oTile-siblings share id&7
    int xcd = id & 7, oTile = (id >> 3) & 3, gidx = id >> 5;
    int g = gidx * 8 + xcd;
    int tt = g & 31, b = (g >> 5) & 3, tensor = (g >> 7) & 1;
    int wave = threadIdx.x >> 6, lane = threadIdx.x & 63;
    int wn = wave & 1, wm = wave >> 1;
    int lane31 = lane & 31, khalf = lane >> 5;
    const f16* bhp = (tensor ? wfhk : wfhq) + ((size_t)(oTile * 4 + wn * 2) * 128) * 512;
    const f16* blp = (tensor ? wflk : wflq) + ((size_t)(oTile * 4 + wn * 2) * 128) * 512;
    const float* src = (tensor ? K : Q) + (size_t)b * Dm * Ll;  // flat [512][2048] view
    f16* dh = (tensor ? ffhk : ffhq);
    f16* dl = (tensor ? fflk : fflq);
    const float scale = tensor ? 1.f : QSCALE;
    const int klen16 = (*flag) << 5;            // 128 or 64 (even)
    const int t0 = (tt * 2 + wm) * 32;
    const int coff = khalf * 8;

    f32x16 acc[2];
#pragma unroll
    for (int j = 0; j < 2; ++j)
#pragma unroll
        for (int r = 0; r < 16; ++r) acc[j][r] = 0.f;

    f16x8 Abh[2], Abl[2], Bbh[2], Bbl[2];       // W ping-pong buffers
    float XA[8], XB[8], mkA, mkB;               // A-source octet ping-pong (f32)
    const size_t lo8 = (size_t)lane * 8;

// load the 8-float S octet for k16=KN into X[], boundary mask into MK
#define LOADX(X, MK, KN) do {                                                        \
    int f_ = (KN) >> 5;                                                              \
    int cb_ = (((KN) >> 2) & 7) * 64 + ((KN) & 3) * 16 + coff;                       \
    int t_ = t0 - 2 + lane31 + f_;                                                   \
    int tc_ = t_ < 0 ? 0 : (t_ > Ll - 1 ? Ll - 1 : t_);                              \
    MK = (t_ == tc_) ? 1.f : 0.f;                                                    \
    const float* sp_ = src + (size_t)cb_ * Ll + tc_;                                 \
    _Pragma("unroll") for (int j_ = 0; j_ < 8; ++j_) X[j_] = sp_[(size_t)j_ * Ll];   \
} while (0)

// convert masked f32 octet to hi/lo f16x8 fragments
#define CVTA(X, MK, AH, AL) do {                                                     \
    _Pragma("unroll") for (int j_ = 0; j_ < 8; ++j_) {                               \
        float x_ = X[j_] * MK; f16 h_ = (f16)x_;                                     \
        AH[j_] = h_; AL[j_] = (f16)(x_ - (float)h_); }                               \
} while (0)

    // prime buffer A with k16=0
    LOADX(XA, mkA, 0);
    Abh[0] = *(const f16x8*)(bhp + lo8);
    Abl[0] = *(const f16x8*)(blp + lo8);
    Abh[1] = *(const f16x8*)(bhp + 128 * 512 + lo8);
    Abl[1] = *(const f16x8*)(blp + 128 * 512 + lo8);

    for (int k16 = 0; k16 < klen16; k16 += 2) {
        {   // prefetch k16+1 into B
            int kn = k16 + 1;
            LOADX(XB, mkB, kn);
            size_t o = (size_t)kn * 512 + lo8;
            Bbh[0] = *(const f16x8*)(bhp + o);
            Bbl[0] = *(const f16x8*)(blp + o);
            Bbh[1] = *(const f16x8*)(bhp + 128 * 512 + o);
            Bbl[1] = *(const f16x8*)(blp + 128 * 512 + o);
        }
        {
            f16x8 Ah, Al;
            CVTA(XA, mkA, Ah, Al);
#pragma unroll
            for (int j = 0; j < 2; ++j) {
                acc[j] = MFMA32(Ah, Abh[j], acc[j]);
                acc[j] = MFMA32(Ah, Abl[j], acc[j]);
                acc[j] = MFMA32(Al, Abh[j], acc[j]);
            }
        }
        {   // prefetch k16+2 into A
            int kn = k16 + 2 < klen16 ? k16 + 2 : klen16 - 1;
            LOADX(XA, mkA, kn);
            size_t o = (size_t)kn * 512 + lo8;
            Abh[0] = *(const f16x8*)(bhp + o);
            Abl[0] = *(const f16x8*)(blp + o);
            Abh[1] = *(const f16x8*)(bhp + 128 * 512 + o);
            Abl[1] = *(const f16x8*)(blp + 128 * 512 + o);
        }
        {
            f16x8 Bh, Bl;
            CVTA(XB, mkB, Bh, Bl);
#pragma unroll
            for (int j = 0; j < 2; ++j) {
                acc[j] = MFMA32(Bh, Bbh[j], acc[j]);
                acc[j] = MFMA32(Bh, Bbl[j], acc[j]);
                acc[j] = MFMA32(Bl, Bbh[j], acc[j]);
            }
        }
    }
#undef LOADX
#undef CVTA
    // epilogue v2: stage wave's 32x64 C tile (hi/lo) in LDS, write f16x8 chunks.
    const int lcol = oTile * 2 + wn;            // ocol>>6, constant per wave
#pragma unroll
    for (int j = 0; j < 2; ++j) {
#pragma unroll
        for (int r = 0; r < 16; ++r) {
            int tl = (r & 3) + ((r >> 2) << 3) + (khalf << 2);   // 0..31
            int trow = tt * 64 + wm * 32 + tl;
            int h = trow >> 8;
            int l = ((trow & 255) << 3) + lcol;
            int d = j * 32 + lane31;
            float v2 = (acc[j][r] + src[((size_t)h * Ll + l) * Dk + d]) * scale;
            f16 hi = (f16)v2;
            est[wave][0][tl][lane31] = hi;
            est[wave][1][tl][lane31] = (f16)(v2 - (float)hi);
        }
        __asm__ volatile("s_waitcnt lgkmcnt(0)" ::: "memory");   // wave-private LDS RAW
#pragma unroll
        for (int c = 0; c < 2; ++c) {
            int id2 = c * 64 + lane;            // 0..127
            int row = id2 >> 2;                 // t_local 0..31
            int dc = id2 & 3;                   // 8-col chunk within j's 32 cols
            int trow = tt * 64 + wm * 32 + row;
            int h = trow >> 8;
            int l = ((trow & 255) << 3) + lcol;
            size_t base2 = ((size_t)(b * 8 + h) * 64 + (l >> 5)) * 4;
            size_t idx = (base2 + j * 2 + (dc >> 1)) * 512 + (size_t)(dc & 1) * 256 + (l & 31) * 8;
            f16x8 hv = *(const f16x8*)&est[wave][0][row][dc * 8];
            f16x8 lv = *(const f16x8*)&est[wave][1][row][dc * 8];
            *(f16x8*)(dh + idx) = hv;
            *(f16x8*)(dl + idx) = lv;
        }
        __asm__ volatile("s_waitcnt lgkmcnt(0)" ::: "memory");   // reads done before next j WAR
    }
}

// ---------------- F: fused attention, K-split across wave pairs ----------------
// R4 config (best measured): 2 blk/CU, superstep 8, 1KB-per-row cached bursts,
// sbuf/combuf union.
#define LOADK(DST, CH) do { size_t kb_ = (size_t)(CH) * 2048 + lane * 8;            \
    _Pragma("unroll") for (int ks_ = 0; ks_ < 4; ++ks_) {                           \
        DST[2 * ks_]     = *(const f16x8*)(kbh + kb_ + ks_ * 512);                  \
        DST[2 * ks_ + 1] = *(const f16x8*)(kbl + kb_ + ks_ * 512); } } while (0)

#define QKM(SRC, ACC) do { _Pragma("unroll") for (int ks_ = 0; ks_ < 4; ++ks_) {    \
        ACC = MFMA32(a_h[ks_], SRC[2 * ks_], ACC);                                  \
        ACC = MFMA32(a_h[ks_], SRC[2 * ks_ + 1], ACC);                              \
        ACC = MFMA32(a_l[ks_], SRC[2 * ks_], ACC); } } while (0)

#define SMUPD(ACC) do { _Pragma("unroll") for (int r_ = 0; r_ < 16; ++r_) {         \
        float v_ = ACC[r_]; float d_ = v_ - m[r_]; float e_ = exp2f(-fabsf(d_));    \
        bool gt_ = d_ > 0.f;                                                        \
        s[r_] = gt_ ? __fmaf_rn(s[r_], e_, 1.f) : (s[r_] + e_);                     \
        m[r_] = gt_ ? v_ : m[r_]; } } while (0)

#define LOADV(DST, CH) do { _Pragma("unroll") for (int q_ = 0; q_ < 4; ++q_) {      \
        int n_ = q_ >> 1, ks2_ = q_ & 1;                                            \
        size_t off_ = ((((size_t)bh * 2 + n_) * 128 + (CH) * 2 + ks2_) * 64 + lane) * 8; \
        DST[q_] = *(const f16x8*)(vf + off_); } } while (0)

union SMemU {
    float combuf[2][32][64];   // 16 KB exchange buffer (softmax combine, ctx reduce)
    f16 sbuf[4][32][264];      // 66 KB P stage: 528B rows (132w % 32 == 4, same
                               // conflict-free b128 class as proven 136-row layout)
};

__global__ __launch_bounds__(256, 2) void kattn(
    const f16* __restrict__ qfh, const f16* __restrict__ qfl,
    const f16* __restrict__ kfh, const f16* __restrict__ kfl,
    const f16* __restrict__ vf,
    float* __restrict__ ctx_out, float* __restrict__ attn_out) {
    __shared__ __align__(16) SMemU sm;
    int id = blockIdx.x;                              // 1024; 4 bh per XCD for K/V L2 locality
    int bh = (id & 7) * 4 + (id >> 8);
    int qt = (id >> 3) & 31;
    int wave = threadIdx.x >> 6, lane = threadIdx.x & 63;
    int qg = wave >> 1, kg = wave & 1;
    int lane31 = lane & 31, khalf = lane >> 5;
    int q0 = qt * 64 + qg * 32;

    // resident Q fragments (hi/lo): 4 ksteps of 16 over d_k=64, contiguous 1KB loads
    f16x8 a_h[4], a_l[4];
    {
        size_t qb = ((size_t)bh * 64 + qt * 2 + qg) * 4;
#pragma unroll
        for (int ks = 0; ks < 4; ++ks) {
            a_h[ks] = *(const f16x8*)(qfh + ((qb + ks) * 64 + lane) * 8);
            a_l[ks] = *(const f16x8*)(qfl + ((qb + ks) * 64 + lane) * 8);
        }
    }
    const f16* kbh = kfh + (size_t)bh * 131072;
    const f16* kbl = kfl + (size_t)bh * 131072;
    const int ch0 = kg * 32, ch1 = ch0 + 32;

    float m[16], s[16];
#pragma unroll
    for (int r = 0; r < 16; ++r) { m[r] = -3.0e38f; s[r] = 0.f; }

    // ---- pass 1: online row max + sum of 2^z, K register ping-pong ----
    {
        f16x8 KA[8], KB[8];
        LOADK(KA, ch0);
        for (int ch = ch0; ch < ch1; ch += 2) {
            LOADK(KB, ch + 1);
            f32x16 acc;
#pragma unroll
            for (int r = 0; r < 16; ++r) acc[r] = 0.f;
            QKM(KA, acc);
            SMUPD(acc);
            {
                int chn = (ch + 2 < ch1) ? ch + 2 : ch;
                LOADK(KA, chn);
            }
            f32x16 acc2;
#pragma unroll
            for (int r = 0; r < 16; ++r) acc2[r] = 0.f;
            QKM(KB, acc2);
            SMUPD(acc2);
        }
    }
    // lane combine within the 32 col-lanes of each half
#pragma unroll
    for (int r = 0; r < 16; ++r) {
        float mm = m[r], ss = s[r];
#pragma unroll
        for (int off = 1; off < 32; off <<= 1) {
            float mo = __shfl_xor(mm, off, 64);
            float so = __shfl_xor(ss, off, 64);
            float mn = fmaxf(mm, mo);
            ss = ss * exp2f(mm - mn) + so * exp2f(mo - mn);
            mm = mn;
        }
        m[r] = mm; s[r] = ss;
    }
    // cross-wave (k-split) combine through LDS
    if (kg == 1) {
#pragma unroll
        for (int r = 0; r < 16; ++r) {
            sm.combuf[qg][r][lane] = m[r];
            sm.combuf[qg][16 + r][lane] = s[r];
        }
    }
    __syncthreads();
    if (kg == 0) {
#pragma unroll
        for (int r = 0; r < 16; ++r) {
            float m1 = sm.combuf[qg][r][lane];
            float s1 = sm.combuf[qg][16 + r][lane];
            float mn = fmaxf(m[r], m1);
            float ss = s[r] * exp2f(m[r] - mn) + s1 * exp2f(m1 - mn);
            m[r] = mn; s[r] = 1.f / ss;
            sm.combuf[qg][r][lane] = mn;
            sm.combuf[qg][16 + r][lane] = s[r];
        }
    }
    __syncthreads();
    if (kg == 1) {
#pragma unroll
        for (int r = 0; r < 16; ++r) {
            m[r] = sm.combuf[qg][r][lane];
            s[r] = sm.combuf[qg][16 + r][lane];
        }
    }
    __syncthreads();   // union hazard: combuf reads must finish before sbuf writes

    f32x16 ctx[2];
#pragma unroll
    for (int n = 0; n < 2; ++n)
#pragma unroll
        for (int r = 0; r < 16; ++r) ctx[n][r] = 0.f;

    const size_t rowbase = ((size_t)bh * Ll + q0) * Ll;

    // ---- pass 2: recompute scores (identical op order), stage P in LDS, PV,
    //      then sweep 256-col batches to attn_out as 1KB-per-row bursts ----
    {
        f16x8 KV[8], VV[4];
        LOADK(KV, ch0);
        LOADV(VV, ch0);
        for (int chb = ch0; chb < ch1; chb += 8) {
#pragma unroll
            for (int i = 0; i < 8; ++i) {
                int ch = chb + i;
                f32x16 acc;
#pragma unroll
                for (int r = 0; r < 16; ++r) acc[r] = 0.f;
                QKM(KV, acc);
                int chn = (ch + 1 < ch1) ? ch + 1 : ch;
                LOADK(KV, chn);              // WAR on KV: safe after MFMA issue; covered by tail
#pragma unroll
                for (int r = 0; r < 16; ++r) {
                    float p = exp2f(acc[r] - m[r]) * s[r];
                    int row = (r & 3) + ((r >> 2) << 3) + (khalf << 2);
                    sm.sbuf[wave][row][i * 32 + lane31] = (f16)p;
                }
                __asm__ volatile("s_waitcnt lgkmcnt(0)" ::: "memory");  // wave-private LDS RAW
#pragma unroll
                for (int ks2 = 0; ks2 < 2; ++ks2) {
                    f16x8 pa = *(const f16x8*)&sm.sbuf[wave][lane31][i * 32 + ks2 * 16 + khalf * 8];
                    ctx[0] = MFMA32(pa, VV[ks2], ctx[0]);
                    ctx[1] = MFMA32(pa, VV[2 + ks2], ctx[1]);
                }
                LOADV(VV, chn);              // covered by next QK cluster
            }
            // store sweep: 32 rows x 256 cols, 1KB contiguous per row, cached stores
#pragma unroll
            for (int ri = 0; ri < 16; ++ri) {
                int row = ri * 2 + khalf;
                f16x8 pv = *(const f16x8*)&sm.sbuf[wave][row][lane31 * 8];
                f32x4 o0 = {(float)pv[0], (float)pv[1], (float)pv[2], (float)pv[3]};
                f32x4 o1 = {(float)pv[4], (float)pv[5], (float)pv[6], (float)pv[7]};
                float* dst = attn_out + rowbase + (size_t)row * Ll + chb * 32 + lane31 * 8;
                *(f32x4*)dst = o0;
                *(f32x4*)(dst + 4) = o1;
            }
        }
    }
    // ---- k-split ctx reduction ----
    __syncthreads();
    if (kg == 1) {
#pragma unroll
        for (int n = 0; n < 2; ++n)
#pragma unroll
            for (int r = 0; r < 16; ++r) sm.combuf[qg][n * 16 + r][lane] = ctx[n][r];
    }
    __syncthreads();
    if (kg == 0) {
#pragma unroll
        for (int n = 0; n < 2; ++n)
#pragma unroll
            for (int r = 0; r < 16; ++r) {
                float v = ctx[n][r] + sm.combuf[qg][n * 16 + r][lane];
                int row = (r & 3) + ((r >> 2) << 3) + (khalf << 2);
                ctx_out[((size_t)bh * Ll + q0 + row) * Dk + n * 32 + lane31] = v;
            }
    }
}

extern "C" void kernel_launch(void* const* d_in, const int* in_sizes, int n_in,
                              void* d_out, int out_size, void* d_ws, size_t ws_size,
                              hipStream_t stream) {
    const float* Q = (const float*)d_in[0];
    const float* K = (const float*)d_in[1];
    const float* V = (const float*)d_in[2];
    // d_in[3] = attn_mask (all-false, unused)
    const float* convq = (const float*)d_in[4];
    const float* convk = (const float*)d_in[5];
    const float* w = (const float*)d_in[6];

    char* ws = (char*)d_ws;
    int* flag = (int*)ws;
    f16* wfhq = (f16*)(ws + OFF_WF);
    f16* wflq = wfhq + NWF;
    f16* wfhk = wflq + NWF;
    f16* wflk = wfhk + NWF;
    f16* ffhq = (f16*)(ws + OFF_FF);
    f16* fflq = ffhq + NFF;
    f16* ffhk = fflq + NFF;
    f16* fflk = ffhk + NFF;
    f16* vf = (f16*)(ws + OFF_VF);

    float* ctx_out = (float*)d_out;
    float* attn_out = ctx_out + (size_t)BH * Ll * Dk;

    kprep_w<<<dim3(128, 2), 256, 0, stream>>>(convq, convk, w, flag, wfhq, wflq, wfhk, wflk);
    kprep_v<<<dim3(16, 32), 256, 0, stream>>>(V, vf);
    kconv<<<dim3(1024), 256, 0, stream>>>(Q, K, flag,
                                          wfhq, wflq, wfhk, wflk, ffhq, fflq, ffhk, fflk);
    kattn<<<dim3(1024), 256, 0, stream>>>(ffhq, fflq, ffhk, fflk, vf, ctx_out, attn_out);
}

// Round 11
// 915.236 us; speedup vs baseline: 1.4791x; 1.0551x over previous
//
#include <hip/hip_runtime.h>

typedef _Float16 f16;
typedef _Float16 f16x4 __attribute__((ext_vector_type(4)));
typedef _Float16 f16x8 __attribute__((ext_vector_type(8)));
typedef float f32x4 __attribute__((ext_vector_type(4)));
typedef float f32x16 __attribute__((ext_vector_type(16)));

#define MFMA32(A, B, C) __builtin_amdgcn_mfma_f32_32x32x16_f16(A, B, C, 0, 0, 0)

constexpr int Bb = 4, Hh = 8, Ll = 2048, Dk = 64, Dm = 512, BH = 32;

// element counts per (tensor,hilo) array
constexpr size_t NWF = (size_t)16 * 128 * 64 * 8;      // W frag: [ob16][k16:128][lane][8]
constexpr size_t NFF = (size_t)BH * 64 * 4 * 64 * 8;   // Qc/Kc frag: [bh][lb64][d16:4][lane][8]
constexpr size_t NVF = (size_t)BH * 2 * 128 * 64 * 8;  // V frag: [bh][db2][l16:128][lane][8]

constexpr size_t OFF_WF = 256;
constexpr size_t OFF_FF = OFF_WF + 4 * NWF * sizeof(f16);
constexpr size_t OFF_VF = OFF_FF + 4 * NFF * sizeof(f16);

// scores computed in base-2: fold log2(e)/sqrt(64) into Qc (exact softmax identity)
#define QSCALE 0.1803368801111204f

// ---------------- P1: mask + split conv weights into frag order ----------------
__global__ void kprep_w(const float* __restrict__ convq, const float* __restrict__ convk,
                        const float* __restrict__ w, int* __restrict__ flag,
                        f16* __restrict__ wfhq, f16* __restrict__ wflq,
                        f16* __restrict__ wfhk, f16* __restrict__ wflk) {
    const int len = (4.f * w[1] > 2.f * w[0]) ? 4 : 2;   // argmax([2w0,4w1]) -> FILTER_LENGTHS[ind]
    if (blockIdx.x == 0 && blockIdx.y == 0 && threadIdx.x == 0) *flag = len;
    int g = blockIdx.x * 256 + threadIdx.x;              // [0,32768) = c8*512 + o
    int o = g & 511, c8 = g >> 9;                        // c = c8*8 + cc
    const float* conv = blockIdx.y ? convk : convq;
    f16* dh = blockIdx.y ? wfhk : wfhq;
    f16* dl = blockIdx.y ? wflk : wflq;
    float4 v[8];
#pragma unroll
    for (int cc = 0; cc < 8; ++cc)                       // coalesced: lanes read consecutive float4
        v[cc] = *(const float4*)(conv + ((size_t)(c8 * 8 + cc) * 512 + o) * 4);
    int ob = o >> 5;
#pragma unroll
    for (int f = 0; f < 4; ++f) {
        f16x8 hv, lv;
#pragma unroll
        for (int cc = 0; cc < 8; ++cc) {
            float x = (f < len) ? ((const float*)&v[cc])[f] : 0.f;
            f16 hi = (f16)x;
            hv[cc] = hi; lv[cc] = (f16)(x - (float)hi);
        }
        // k = f*512 + c8*8 + cc: k&7=cc, (k>>3)&1=c8&1, k16=f*32+(c8>>1)
        int k16 = f * 32 + (c8 >> 1);
        size_t base = (((size_t)ob * 128 + k16) * 64 + (c8 & 1) * 32 + (o & 31)) * 8;
        *(f16x8*)(dh + base) = hv;
        *(f16x8*)(dl + base) = lv;
    }
}

// ---------------- P3: V -> frag order for PV B-operand ----------------
__global__ void kprep_v(const float* __restrict__ V, f16* __restrict__ vf) {
    int bh = blockIdx.y, l0 = blockIdx.x * 128;
    int tid = threadIdx.x;
    const float* src = V + (size_t)bh * Ll * Dk;
#pragma unroll
    for (int s = 0; s < 4; ++s) {
        int g = s * 4 + (tid >> 6);
        int lane = tid & 63;
        int l16s = g >> 1, db = g & 1;
        int khalf = lane >> 5, lane31 = lane & 31;
        int d = db * 32 + lane31;
        f16x8 out;
#pragma unroll
        for (int j = 0; j < 8; ++j) {
            int l = l0 + l16s * 16 + khalf * 8 + j;
            out[j] = (f16)src[(size_t)l * Dk + d];
        }
        size_t idx = ((((size_t)bh * 2 + db) * 128 + (l0 >> 4) + l16s) * 64 + lane) * 8;
        *(f16x8*)(vf + idx) = out;
    }
}

// ---------------- C: conv GEMM, fused A-operand + LDS-transposed epilogue ----------------
// (unchanged from R10)
__global__ __launch_bounds__(256, 4) void kconv(
    const float* __restrict__ Q, const float* __restrict__ K, const int* __restrict__ flag,
    const f16* __restrict__ wfhq, const f16* __restrict__ wflq,
    const f16* __restrict__ wfhk, const f16* __restrict__ wflk,
    f16* __restrict__ ffhq, f16* __restrict__ fflq,
    f16* __restrict__ ffhk, f16* __restrict__ fflk) {
    __shared__ __align__(16) f16 est[4][2][32][40];   // 20.5 KB
    int id = blockIdx.x;                        // R4 swizzle: 4 oTile-siblings share id&7
    int xcd = id & 7, oTile = (id >> 3) & 3, gidx = id >> 5;
    int g = gidx * 8 + xcd;
    int tt = g & 31, b = (g >> 5) & 3, tensor = (g >> 7) & 1;
    int wave = threadIdx.x >> 6, lane = threadIdx.x & 63;
    int wn = wave & 1, wm = wave >> 1;
    int lane31 = lane & 31, khalf = lane >> 5;
    const f16* bhp = (tensor ? wfhk : wfhq) + ((size_t)(oTile * 4 + wn * 2) * 128) * 512;
    const f16* blp = (tensor ? wflk : wflq) + ((size_t)(oTile * 4 + wn * 2) * 128) * 512;
    const float* src = (tensor ? K : Q) + (size_t)b * Dm * Ll;  // flat [512][2048] view
    f16* dh = (tensor ? ffhk : ffhq);
    f16* dl = (tensor ? fflk : fflq);
    const float scale = tensor ? 1.f : QSCALE;
    const int klen16 = (*flag) << 5;            // 128 or 64 (even)
    const int t0 = (tt * 2 + wm) * 32;
    const int coff = khalf * 8;

    f32x16 acc[2];
#pragma unroll
    for (int j = 0; j < 2; ++j)
#pragma unroll
        for (int r = 0; r < 16; ++r) acc[j][r] = 0.f;

    f16x8 Abh[2], Abl[2], Bbh[2], Bbl[2];       // W ping-pong buffers
    float XA[8], XB[8], mkA, mkB;               // A-source octet ping-pong (f32)
    const size_t lo8 = (size_t)lane * 8;

#define LOADX(X, MK, KN) do {                                                        \
    int f_ = (KN) >> 5;                                                              \
    int cb_ = (((KN) >> 2) & 7) * 64 + ((KN) & 3) * 16 + coff;                       \
    int t_ = t0 - 2 + lane31 + f_;                                                   \
    int tc_ = t_ < 0 ? 0 : (t_ > Ll - 1 ? Ll - 1 : t_);                              \
    MK = (t_ == tc_) ? 1.f : 0.f;                                                    \
    const float* sp_ = src + (size_t)cb_ * Ll + tc_;                                 \
    _Pragma("unroll") for (int j_ = 0; j_ < 8; ++j_) X[j_] = sp_[(size_t)j_ * Ll];   \
} while (0)

#define CVTA(X, MK, AH, AL) do {                                                     \
    _Pragma("unroll") for (int j_ = 0; j_ < 8; ++j_) {                               \
        float x_ = X[j_] * MK; f16 h_ = (f16)x_;                                     \
        AH[j_] = h_; AL[j_] = (f16)(x_ - (float)h_); }                               \
} while (0)

    // prime buffer A with k16=0
    LOADX(XA, mkA, 0);
    Abh[0] = *(const f16x8*)(bhp + lo8);
    Abl[0] = *(const f16x8*)(blp + lo8);
    Abh[1] = *(const f16x8*)(bhp + 128 * 512 + lo8);
    Abl[1] = *(const f16x8*)(blp + 128 * 512 + lo8);

    for (int k16 = 0; k16 < klen16; k16 += 2) {
        {   // prefetch k16+1 into B
            int kn = k16 + 1;
            LOADX(XB, mkB, kn);
            size_t o = (size_t)kn * 512 + lo8;
            Bbh[0] = *(const f16x8*)(bhp + o);
            Bbl[0] = *(const f16x8*)(blp + o);
            Bbh[1] = *(const f16x8*)(bhp + 128 * 512 + o);
            Bbl[1] = *(const f16x8*)(blp + 128 * 512 + o);
        }
        {
            f16x8 Ah, Al;
            CVTA(XA, mkA, Ah, Al);
#pragma unroll
            for (int j = 0; j < 2; ++j) {
                acc[j] = MFMA32(Ah, Abh[j], acc[j]);
                acc[j] = MFMA32(Ah, Abl[j], acc[j]);
                acc[j] = MFMA32(Al, Abh[j], acc[j]);
            }
        }
        {   // prefetch k16+2 into A
            int kn = k16 + 2 < klen16 ? k16 + 2 : klen16 - 1;
            LOADX(XA, mkA, kn);
            size_t o = (size_t)kn * 512 + lo8;
            Abh[0] = *(const f16x8*)(bhp + o);
            Abl[0] = *(const f16x8*)(blp + o);
            Abh[1] = *(const f16x8*)(bhp + 128 * 512 + o);
            Abl[1] = *(const f16x8*)(blp + 128 * 512 + o);
        }
        {
            f16x8 Bh, Bl;
            CVTA(XB, mkB, Bh, Bl);
#pragma unroll
            for (int j = 0; j < 2; ++j) {
                acc[j] = MFMA32(Bh, Bbh[j], acc[j]);
                acc[j] = MFMA32(Bh, Bbl[j], acc[j]);
                acc[j] = MFMA32(Bl, Bbh[j], acc[j]);
            }
        }
    }
#undef LOADX
#undef CVTA
    // epilogue: stage wave's 32x64 C tile (hi/lo) in LDS, write f16x8 chunks.
    const int lcol = oTile * 2 + wn;            // ocol>>6, constant per wave
#pragma unroll
    for (int j = 0; j < 2; ++j) {
#pragma unroll
        for (int r = 0; r < 16; ++r) {
            int tl = (r & 3) + ((r >> 2) << 3) + (khalf << 2);   // 0..31
            int trow = tt * 64 + wm * 32 + tl;
            int h = trow >> 8;
            int l = ((trow & 255) << 3) + lcol;
            int d = j * 32 + lane31;
            float v2 = (acc[j][r] + src[((size_t)h * Ll + l) * Dk + d]) * scale;
            f16 hi = (f16)v2;
            est[wave][0][tl][lane31] = hi;
            est[wave][1][tl][lane31] = (f16)(v2 - (float)hi);
        }
        __asm__ volatile("s_waitcnt lgkmcnt(0)" ::: "memory");   // wave-private LDS RAW
#pragma unroll
        for (int c = 0; c < 2; ++c) {
            int id2 = c * 64 + lane;            // 0..127
            int row = id2 >> 2;                 // t_local 0..31
            int dc = id2 & 3;                   // 8-col chunk within j's 32 cols
            int trow = tt * 64 + wm * 32 + row;
            int h = trow >> 8;
            int l = ((trow & 255) << 3) + lcol;
            size_t base2 = ((size_t)(b * 8 + h) * 64 + (l >> 5)) * 4;
            size_t idx = (base2 + j * 2 + (dc >> 1)) * 512 + (size_t)(dc & 1) * 256 + (l & 31) * 8;
            f16x8 hv = *(const f16x8*)&est[wave][0][row][dc * 8];
            f16x8 lv = *(const f16x8*)&est[wave][1][row][dc * 8];
            *(f16x8*)(dh + idx) = hv;
            *(f16x8*)(dl + idx) = lv;
        }
        __asm__ volatile("s_waitcnt lgkmcnt(0)" ::: "memory");   // reads done before next j WAR
    }
}

// ---------------- F: fused attention, K-split across wave pairs ----------------
// R11: pass-2 sweep INTERLEAVED one superstep behind compute (double-buffered
// sbuf, superstep 4). Theory: vmcnt is a single in-order FIFO; the old
// end-of-superstep sweep put 32 stores AHEAD of the next superstep's K-loads,
// so every compiler s_waitcnt before MFMA transitively waited for store-acks
// under L2 dirty backpressure. Now stores are issued AFTER the loads of the
// current ch (always younger than anything compute waits on) and get a full
// ch (~400cyc) to ack before they could gate. 2 blk/CU preserved (68KB LDS).
#define LOADK(DST, CH) do { size_t kb_ = (size_t)(CH) * 2048 + lane * 8;            \
    _Pragma("unroll") for (int ks_ = 0; ks_ < 4; ++ks_) {                           \
        DST[2 * ks_]     = *(const f16x8*)(kbh + kb_ + ks_ * 512);                  \
        DST[2 * ks_ + 1] = *(const f16x8*)(kbl + kb_ + ks_ * 512); } } while (0)

#define QKM(SRC, ACC) do { _Pragma("unroll") for (int ks_ = 0; ks_ < 4; ++ks_) {    \
        ACC = MFMA32(a_h[ks_], SRC[2 * ks_], ACC);                                  \
        ACC = MFMA32(a_h[ks_], SRC[2 * ks_ + 1], ACC);                              \
        ACC = MFMA32(a_l[ks_], SRC[2 * ks_], ACC); } } while (0)

#define SMUPD(ACC) do { _Pragma("unroll") for (int r_ = 0; r_ < 16; ++r_) {         \
        float v_ = ACC[r_]; float d_ = v_ - m[r_]; float e_ = exp2f(-fabsf(d_));    \
        bool gt_ = d_ > 0.f;                                                        \
        s[r_] = gt_ ? __fmaf_rn(s[r_], e_, 1.f) : (s[r_] + e_);                     \
        m[r_] = gt_ ? v_ : m[r_]; } } while (0)

#define LOADV(DST, CH) do { _Pragma("unroll") for (int q_ = 0; q_ < 4; ++q_) {      \
        int n_ = q_ >> 1, ks2_ = q_ & 1;                                            \
        size_t off_ = ((((size_t)bh * 2 + n_) * 128 + (CH) * 2 + ks2_) * 64 + lane) * 8; \
        DST[q_] = *(const f16x8*)(vf + off_); } } while (0)

union SMemU {
    float combuf[2][32][64];   // 16 KB exchange buffer (softmax combine, ctx reduce)
    f16 sbuf[2][4][32][136];   // 68 KB double-buffered P stage: 272B rows
                               // (68w % 32 == 4, proven conflict-free b128 class)
};

__global__ __launch_bounds__(256, 2) void kattn(
    const f16* __restrict__ qfh, const f16* __restrict__ qfl,
    const f16* __restrict__ kfh, const f16* __restrict__ kfl,
    const f16* __restrict__ vf,
    float* __restrict__ ctx_out, float* __restrict__ attn_out) {
    __shared__ __align__(16) SMemU sm;
    int id = blockIdx.x;                              // 1024; 4 bh per XCD for K/V L2 locality
    int bh = (id & 7) * 4 + (id >> 8);
    int qt = (id >> 3) & 31;
    int wave = threadIdx.x >> 6, lane = threadIdx.x & 63;
    int qg = wave >> 1, kg = wave & 1;
    int lane31 = lane & 31, khalf = lane >> 5;
    int q0 = qt * 64 + qg * 32;

    // resident Q fragments (hi/lo): 4 ksteps of 16 over d_k=64, contiguous 1KB loads
    f16x8 a_h[4], a_l[4];
    {
        size_t qb = ((size_t)bh * 64 + qt * 2 + qg) * 4;
#pragma unroll
        for (int ks = 0; ks < 4; ++ks) {
            a_h[ks] = *(const f16x8*)(qfh + ((qb + ks) * 64 + lane) * 8);
            a_l[ks] = *(const f16x8*)(qfl + ((qb + ks) * 64 + lane) * 8);
        }
    }
    const f16* kbh = kfh + (size_t)bh * 131072;
    const f16* kbl = kfl + (size_t)bh * 131072;
    const int ch0 = kg * 32, ch1 = ch0 + 32;

    float m[16], s[16];
#pragma unroll
    for (int r = 0; r < 16; ++r) { m[r] = -3.0e38f; s[r] = 0.f; }

    // ---- pass 1: online row max + sum of 2^z, K register ping-pong ----
    {
        f16x8 KA[8], KB[8];
        LOADK(KA, ch0);
        for (int ch = ch0; ch < ch1; ch += 2) {
            LOADK(KB, ch + 1);
            f32x16 acc;
#pragma unroll
            for (int r = 0; r < 16; ++r) acc[r] = 0.f;
            QKM(KA, acc);
            SMUPD(acc);
            {
                int chn = (ch + 2 < ch1) ? ch + 2 : ch;
                LOADK(KA, chn);
            }
            f32x16 acc2;
#pragma unroll
            for (int r = 0; r < 16; ++r) acc2[r] = 0.f;
            QKM(KB, acc2);
            SMUPD(acc2);
        }
    }
    // lane combine within the 32 col-lanes of each half
#pragma unroll
    for (int r = 0; r < 16; ++r) {
        float mm = m[r], ss = s[r];
#pragma unroll
        for (int off = 1; off < 32; off <<= 1) {
            float mo = __shfl_xor(mm, off, 64);
            float so = __shfl_xor(ss, off, 64);
            float mn = fmaxf(mm, mo);
            ss = ss * exp2f(mm - mn) + so * exp2f(mo - mn);
            mm = mn;
        }
        m[r] = mm; s[r] = ss;
    }
    // cross-wave (k-split) combine through LDS
    if (kg == 1) {
#pragma unroll
        for (int r = 0; r < 16; ++r) {
            sm.combuf[qg][r][lane] = m[r];
            sm.combuf[qg][16 + r][lane] = s[r];
        }
    }
    __syncthreads();
    if (kg == 0) {
#pragma unroll
        for (int r = 0; r < 16; ++r) {
            float m1 = sm.combuf[qg][r][lane];
            float s1 = sm.combuf[qg][16 + r][lane];
            float mn = fmaxf(m[r], m1);
            float ss = s[r] * exp2f(m[r] - mn) + s1 * exp2f(m1 - mn);
            m[r] = mn; s[r] = 1.f / ss;
            sm.combuf[qg][r][lane] = mn;
            sm.combuf[qg][16 + r][lane] = s[r];
        }
    }
    __syncthreads();
    if (kg == 1) {
#pragma unroll
        for (int r = 0; r < 16; ++r) {
            m[r] = sm.combuf[qg][r][lane];
            s[r] = sm.combuf[qg][16 + r][lane];
        }
    }
    __syncthreads();   // union hazard: combuf reads must finish before sbuf writes

    f32x16 ctx[2];
#pragma unroll
    for (int n = 0; n < 2; ++n)
#pragma unroll
        for (int r = 0; r < 16; ++r) ctx[n][r] = 0.f;

    const size_t rowbase = ((size_t)bh * Ll + q0) * Ll;

    // ---- pass 2: recompute scores (identical op order); P staged in dbuf sbuf;
    //      sweep of buffer s-1 interleaved into superstep s (stores always
    //      younger than the loads compute waits on) ----
    {
        f16x8 KV[8], VV[4];
        LOADK(KV, ch0);
        LOADV(VV, ch0);
        int sst = 0;
        for (int chb = ch0; chb < ch1; chb += 4, sst ^= 1) {
#pragma unroll
            for (int i = 0; i < 4; ++i) {
                int ch = chb + i;
                f32x16 acc;
#pragma unroll
                for (int r = 0; r < 16; ++r) acc[r] = 0.f;
                QKM(KV, acc);
                int chn = (ch + 1 < ch1) ? ch + 1 : ch;
                LOADK(KV, chn);              // WAR on KV: safe after MFMA issue
#pragma unroll
                for (int r = 0; r < 16; ++r) {
                    float p = exp2f(acc[r] - m[r]) * s[r];
                    int row = (r & 3) + ((r >> 2) << 3) + (khalf << 2);
                    sm.sbuf[sst][wave][row][i * 32 + lane31] = (f16)p;
                }
                __asm__ volatile("s_waitcnt lgkmcnt(0)" ::: "memory");  // wave-private LDS RAW
#pragma unroll
                for (int ks2 = 0; ks2 < 2; ++ks2) {
                    f16x8 pa = *(const f16x8*)&sm.sbuf[sst][wave][lane31][i * 32 + ks2 * 16 + khalf * 8];
                    ctx[0] = MFMA32(pa, VV[ks2], ctx[0]);
                    ctx[1] = MFMA32(pa, VV[2 + ks2], ctx[1]);
                }
                LOADV(VV, chn);              // covered by next QK cluster
                // interleaved sweep: 4 rows of the PREVIOUS superstep's buffer,
                // issued after this ch's loads -> never older than a needed load
                if (chb > ch0) {
                    int chbp = chb - 4;
#pragma unroll
                    for (int q = 0; q < 4; ++q) {
                        int ri = i * 4 + q;
                        int row = ri * 2 + khalf;
                        f16x4 pv = *(const f16x4*)&sm.sbuf[sst ^ 1][wave][row][lane31 * 4];
                        f32x4 o = {(float)pv[0], (float)pv[1], (float)pv[2], (float)pv[3]};
                        *(f32x4*)(attn_out + rowbase + (size_t)row * Ll + chbp * 32 + lane31 * 4) = o;
                    }
                }
            }
        }
        // epilogue sweep: last superstep's buffer (sst toggled past it -> sst^1)
        {
            int chbp = ch1 - 4;
#pragma unroll
            for (int ri = 0; ri < 16; ++ri) {
                int row = ri * 2 + khalf;
                f16x4 pv = *(const f16x4*)&sm.sbuf[sst ^ 1][wave][row][lane31 * 4];
                f32x4 o = {(float)pv[0], (float)pv[1], (float)pv[2], (float)pv[3]};
                *(f32x4*)(attn_out + rowbase + (size_t)row * Ll + chbp * 32 + lane31 * 4) = o;
            }
        }
    }
    // ---- k-split ctx reduction ----
    __syncthreads();
    if (kg == 1) {
#pragma unroll
        for (int n = 0; n < 2; ++n)
#pragma unroll
            for (int r = 0; r < 16; ++r) sm.combuf[qg][n * 16 + r][lane] = ctx[n][r];
    }
    __syncthreads();
    if (kg == 0) {
#pragma unroll
        for (int n = 0; n < 2; ++n)
#pragma unroll
            for (int r = 0; r < 16; ++r) {
                float v = ctx[n][r] + sm.combuf[qg][n * 16 + r][lane];
                int row = (r & 3) + ((r >> 2) << 3) + (khalf << 2);
                ctx_out[((size_t)bh * Ll + q0 + row) * Dk + n * 32 + lane31] = v;
            }
    }
}

extern "C" void kernel_launch(void* const* d_in, const int* in_sizes, int n_in,
                              void* d_out, int out_size, void* d_ws, size_t ws_size,
                              hipStream_t stream) {
    const float* Q = (const float*)d_in[0];
    const float* K = (const float*)d_in[1];
    const float* V = (const float*)d_in[2];
    // d_in[3] = attn_mask (all-false, unused)
    const float* convq = (const float*)d_in[4];
    const float* convk = (const float*)d_in[5];
    const float* w = (const float*)d_in[6];

    char* ws = (char*)d_ws;
    int* flag = (int*)ws;
    f16* wfhq = (f16*)(ws + OFF_WF);
    f16* wflq = wfhq + NWF;
    f16* wfhk = wflq + NWF;
    f16* wflk = wfhk + NWF;
    f16* ffhq = (f16*)(ws + OFF_FF);
    f16* fflq = ffhq + NFF;
    f16* ffhk = fflq + NFF;
    f16* fflk = ffhk + NFF;
    f16* vf = (f16*)(ws + OFF_VF);

    float* ctx_out = (float*)d_out;
    float* attn_out = ctx_out + (size_t)BH * Ll * Dk;

    kprep_w<<<dim3(128, 2), 256, 0, stream>>>(convq, convk, w, flag, wfhq, wflq, wfhk, wflk);
    kprep_v<<<dim3(16, 32), 256, 0, stream>>>(V, vf);
    kconv<<<dim3(1024), 256, 0, stream>>>(Q, K, flag,
                                          wfhq, wflq, wfhk, wflk, ffhq, fflq, ffhk, fflk);
    kattn<<<dim3(1024), 256, 0, stream>>>(ffhq, fflq, ffhk, fflk, vf, ctx_out, attn_out);
}

// Round 12
// 913.187 us; speedup vs baseline: 1.4824x; 1.0022x over previous
//
#include <hip/hip_runtime.h>

typedef _Float16 f16;
typedef _Float16 f16x4 __attribute__((ext_vector_type(4)));
typedef _Float16 f16x8 __attribute__((ext_vector_type(8)));
typedef float f32x4 __attribute__((ext_vector_type(4)));
typedef float f32x16 __attribute__((ext_vector_type(16)));

#define MFMA32(A, B, C) __builtin_amdgcn_mfma_f32_32x32x16_f16(A, B, C, 0, 0, 0)

constexpr int Bb = 4, Hh = 8, Ll = 2048, Dk = 64, Dm = 512, BH = 32;

// element counts per (tensor,hilo) array
constexpr size_t NWF = (size_t)16 * 128 * 64 * 8;      // W frag: [ob16][k16:128][lane][8]
constexpr size_t NFF = (size_t)BH * 64 * 4 * 64 * 8;   // Qc/Kc frag: [bh][lb64][d16:4][lane][8]
constexpr size_t NVF = (size_t)BH * 2 * 128 * 64 * 8;  // V frag: [bh][db2][l16:128][lane][8]

constexpr size_t OFF_WF = 256;
constexpr size_t OFF_FF = OFF_WF + 4 * NWF * sizeof(f16);
constexpr size_t OFF_VF = OFF_FF + 4 * NFF * sizeof(f16);

// scores computed in base-2: fold log2(e)/sqrt(64) into Qc (exact softmax identity)
#define QSCALE 0.1803368801111204f

// ---------------- P1: mask + split conv weights into frag order ----------------
__global__ void kprep_w(const float* __restrict__ convq, const float* __restrict__ convk,
                        const float* __restrict__ w, int* __restrict__ flag,
                        f16* __restrict__ wfhq, f16* __restrict__ wflq,
                        f16* __restrict__ wfhk, f16* __restrict__ wflk) {
    const int len = (4.f * w[1] > 2.f * w[0]) ? 4 : 2;   // argmax([2w0,4w1]) -> FILTER_LENGTHS[ind]
    if (blockIdx.x == 0 && blockIdx.y == 0 && threadIdx.x == 0) *flag = len;
    int g = blockIdx.x * 256 + threadIdx.x;              // [0,32768) = c8*512 + o
    int o = g & 511, c8 = g >> 9;                        // c = c8*8 + cc
    const float* conv = blockIdx.y ? convk : convq;
    f16* dh = blockIdx.y ? wfhk : wfhq;
    f16* dl = blockIdx.y ? wflk : wflq;
    float4 v[8];
#pragma unroll
    for (int cc = 0; cc < 8; ++cc)                       // coalesced: lanes read consecutive float4
        v[cc] = *(const float4*)(conv + ((size_t)(c8 * 8 + cc) * 512 + o) * 4);
    int ob = o >> 5;
#pragma unroll
    for (int f = 0; f < 4; ++f) {
        f16x8 hv, lv;
#pragma unroll
        for (int cc = 0; cc < 8; ++cc) {
            float x = (f < len) ? ((const float*)&v[cc])[f] : 0.f;
            f16 hi = (f16)x;
            hv[cc] = hi; lv[cc] = (f16)(x - (float)hi);
        }
        // k = f*512 + c8*8 + cc: k&7=cc, (k>>3)&1=c8&1, k16=f*32+(c8>>1)
        int k16 = f * 32 + (c8 >> 1);
        size_t base = (((size_t)ob * 128 + k16) * 64 + (c8 & 1) * 32 + (o & 31)) * 8;
        *(f16x8*)(dh + base) = hv;
        *(f16x8*)(dl + base) = lv;
    }
}

// ---------------- P3: V -> frag order for PV B-operand ----------------
__global__ void kprep_v(const float* __restrict__ V, f16* __restrict__ vf) {
    int bh = blockIdx.y, l0 = blockIdx.x * 128;
    int tid = threadIdx.x;
    const float* src = V + (size_t)bh * Ll * Dk;
#pragma unroll
    for (int s = 0; s < 4; ++s) {
        int g = s * 4 + (tid >> 6);
        int lane = tid & 63;
        int l16s = g >> 1, db = g & 1;
        int khalf = lane >> 5, lane31 = lane & 31;
        int d = db * 32 + lane31;
        f16x8 out;
#pragma unroll
        for (int j = 0; j < 8; ++j) {
            int l = l0 + l16s * 16 + khalf * 8 + j;
            out[j] = (f16)src[(size_t)l * Dk + d];
        }
        size_t idx = ((((size_t)bh * 2 + db) * 128 + (l0 >> 4) + l16s) * 64 + lane) * 8;
        *(f16x8*)(vf + idx) = out;
    }
}

// ---------------- C: conv GEMM, 512-thread blocks (8 waves = 4 wm x 2 wn) ----------------
// R12: each W stream now feeds FOUR wm-waves (was 2) -> per-CU L2 W-traffic and
// device-wide W reads halved (~1GB -> ~512MB); grid 512 = exactly 2 blocks/CU,
// one generation, same 16 waves/CU and same per-wave VGPR cap (128). Per-wave
// code identical to R10/R11 (fused A-operand, W ping-pong, LDS epilogue).
// Swizzle property preserved: xcd=id&7, 4 oB-siblings of one (tensor,b,ttB)
// share an XCD (activation L2 sharing + ff-write locality for kattn).
__global__ __launch_bounds__(512, 2) void kconv(
    const float* __restrict__ Q, const float* __restrict__ K, const int* __restrict__ flag,
    const f16* __restrict__ wfhq, const f16* __restrict__ wflq,
    const f16* __restrict__ wfhk, const f16* __restrict__ wflk,
    f16* __restrict__ ffhq, f16* __restrict__ fflq,
    f16* __restrict__ ffhk, f16* __restrict__ fflk) {
    __shared__ __align__(16) f16 est[8][2][32][40];   // 40 KB
    int id = blockIdx.x;
    int xcd = id & 7, oB = (id >> 3) & 3, gidx = id >> 5;     // gidx in [0,16)
    int g = gidx * 8 + xcd;                                   // [0,128)
    int ttB = g & 15, b = (g >> 4) & 3, tensor = (g >> 6) & 1;
    int wave = threadIdx.x >> 6, lane = threadIdx.x & 63;     // wave in [0,8)
    int wn = wave & 1, wm = wave >> 1;                        // wm in [0,4)
    int lane31 = lane & 31, khalf = lane >> 5;
    const f16* bhp = (tensor ? wfhk : wfhq) + ((size_t)(oB * 4 + wn * 2) * 128) * 512;
    const f16* blp = (tensor ? wflk : wflq) + ((size_t)(oB * 4 + wn * 2) * 128) * 512;
    const float* src = (tensor ? K : Q) + (size_t)b * Dm * Ll;  // flat [512][2048] view
    f16* dh = (tensor ? ffhk : ffhq);
    f16* dl = (tensor ? fflk : fflq);
    const float scale = tensor ? 1.f : QSCALE;
    const int klen16 = (*flag) << 5;            // 128 or 64 (even)
    const int t0 = (ttB * 4 + wm) * 32;
    const int coff = khalf * 8;

    f32x16 acc[2];
#pragma unroll
    for (int j = 0; j < 2; ++j)
#pragma unroll
        for (int r = 0; r < 16; ++r) acc[j][r] = 0.f;

    f16x8 Abh[2], Abl[2], Bbh[2], Bbl[2];       // W ping-pong buffers
    float XA[8], XB[8], mkA, mkB;               // A-source octet ping-pong (f32)
    const size_t lo8 = (size_t)lane * 8;

#define LOADX(X, MK, KN) do {                                                        \
    int f_ = (KN) >> 5;                                                              \
    int cb_ = (((KN) >> 2) & 7) * 64 + ((KN) & 3) * 16 + coff;                       \
    int t_ = t0 - 2 + lane31 + f_;                                                   \
    int tc_ = t_ < 0 ? 0 : (t_ > Ll - 1 ? Ll - 1 : t_);                              \
    MK = (t_ == tc_) ? 1.f : 0.f;                                                    \
    const float* sp_ = src + (size_t)cb_ * Ll + tc_;                                 \
    _Pragma("unroll") for (int j_ = 0; j_ < 8; ++j_) X[j_] = sp_[(size_t)j_ * Ll];   \
} while (0)

#define CVTA(X, MK, AH, AL) do {                                                     \
    _Pragma("unroll") for (int j_ = 0; j_ < 8; ++j_) {                               \
        float x_ = X[j_] * MK; f16 h_ = (f16)x_;                                     \
        AH[j_] = h_; AL[j_] = (f16)(x_ - (float)h_); }                               \
} while (0)

    // prime buffer A with k16=0
    LOADX(XA, mkA, 0);
    Abh[0] = *(const f16x8*)(bhp + lo8);
    Abl[0] = *(const f16x8*)(blp + lo8);
    Abh[1] = *(const f16x8*)(bhp + 128 * 512 + lo8);
    Abl[1] = *(const f16x8*)(blp + 128 * 512 + lo8);

    for (int k16 = 0; k16 < klen16; k16 += 2) {
        {   // prefetch k16+1 into B
            int kn = k16 + 1;
            LOADX(XB, mkB, kn);
            size_t o = (size_t)kn * 512 + lo8;
            Bbh[0] = *(const f16x8*)(bhp + o);
            Bbl[0] = *(const f16x8*)(blp + o);
            Bbh[1] = *(const f16x8*)(bhp + 128 * 512 + o);
            Bbl[1] = *(const f16x8*)(blp + 128 * 512 + o);
        }
        {
            f16x8 Ah, Al;
            CVTA(XA, mkA, Ah, Al);
#pragma unroll
            for (int j = 0; j < 2; ++j) {
                acc[j] = MFMA32(Ah, Abh[j], acc[j]);
                acc[j] = MFMA32(Ah, Abl[j], acc[j]);
                acc[j] = MFMA32(Al, Abh[j], acc[j]);
            }
        }
        {   // prefetch k16+2 into A
            int kn = k16 + 2 < klen16 ? k16 + 2 : klen16 - 1;
            LOADX(XA, mkA, kn);
            size_t o = (size_t)kn * 512 + lo8;
            Abh[0] = *(const f16x8*)(bhp + o);
            Abl[0] = *(const f16x8*)(blp + o);
            Abh[1] = *(const f16x8*)(bhp + 128 * 512 + o);
            Abl[1] = *(const f16x8*)(blp + 128 * 512 + o);
        }
        {
            f16x8 Bh, Bl;
            CVTA(XB, mkB, Bh, Bl);
#pragma unroll
            for (int j = 0; j < 2; ++j) {
                acc[j] = MFMA32(Bh, Bbh[j], acc[j]);
                acc[j] = MFMA32(Bh, Bbl[j], acc[j]);
                acc[j] = MFMA32(Bl, Bbh[j], acc[j]);
            }
        }
    }
#undef LOADX
#undef CVTA
    // epilogue: stage wave's 32x64 C tile (hi/lo) in LDS, write f16x8 chunks.
    const int lcol = oB * 2 + wn;               // ocol>>6, constant per wave
#pragma unroll
    for (int j = 0; j < 2; ++j) {
#pragma unroll
        for (int r = 0; r < 16; ++r) {
            int tl = (r & 3) + ((r >> 2) << 3) + (khalf << 2);   // 0..31
            int trow = ttB * 128 + wm * 32 + tl;
            int h = trow >> 8;
            int l = ((trow & 255) << 3) + lcol;
            int d = j * 32 + lane31;
            float v2 = (acc[j][r] + src[((size_t)h * Ll + l) * Dk + d]) * scale;
            f16 hi = (f16)v2;
            est[wave][0][tl][lane31] = hi;
            est[wave][1][tl][lane31] = (f16)(v2 - (float)hi);
        }
        __asm__ volatile("s_waitcnt lgkmcnt(0)" ::: "memory");   // wave-private LDS RAW
#pragma unroll
        for (int c = 0; c < 2; ++c) {
            int id2 = c * 64 + lane;            // 0..127
            int row = id2 >> 2;                 // t_local 0..31
            int dc = id2 & 3;                   // 8-col chunk within j's 32 cols
            int trow = ttB * 128 + wm * 32 + row;
            int h = trow >> 8;
            int l = ((trow & 255) << 3) + lcol;
            size_t base2 = ((size_t)(b * 8 + h) * 64 + (l >> 5)) * 4;
            size_t idx = (base2 + j * 2 + (dc >> 1)) * 512 + (size_t)(dc & 1) * 256 + (l & 31) * 8;
            f16x8 hv = *(const f16x8*)&est[wave][0][row][dc * 8];
            f16x8 lv = *(const f16x8*)&est[wave][1][row][dc * 8];
            *(f16x8*)(dh + idx) = hv;
            *(f16x8*)(dl + idx) = lv;
        }
        __asm__ volatile("s_waitcnt lgkmcnt(0)" ::: "memory");   // reads done before next j WAR
    }
}

// ---------------- F: fused attention, K-split across wave pairs ----------------
// (unchanged from R11: interleaved-sweep double-buffered P stage, 2 blk/CU)
#define LOADK(DST, CH) do { size_t kb_ = (size_t)(CH) * 2048 + lane * 8;            \
    _Pragma("unroll") for (int ks_ = 0; ks_ < 4; ++ks_) {                           \
        DST[2 * ks_]     = *(const f16x8*)(kbh + kb_ + ks_ * 512);                  \
        DST[2 * ks_ + 1] = *(const f16x8*)(kbl + kb_ + ks_ * 512); } } while (0)

#define QKM(SRC, ACC) do { _Pragma("unroll") for (int ks_ = 0; ks_ < 4; ++ks_) {    \
        ACC = MFMA32(a_h[ks_], SRC[2 * ks_], ACC);                                  \
        ACC = MFMA32(a_h[ks_], SRC[2 * ks_ + 1], ACC);                              \
        ACC = MFMA32(a_l[ks_], SRC[2 * ks_], ACC); } } while (0)

#define SMUPD(ACC) do { _Pragma("unroll") for (int r_ = 0; r_ < 16; ++r_) {         \
        float v_ = ACC[r_]; float d_ = v_ - m[r_]; float e_ = exp2f(-fabsf(d_));    \
        bool gt_ = d_ > 0.f;                                                        \
        s[r_] = gt_ ? __fmaf_rn(s[r_], e_, 1.f) : (s[r_] + e_);                     \
        m[r_] = gt_ ? v_ : m[r_]; } } while (0)

#define LOADV(DST, CH) do { _Pragma("unroll") for (int q_ = 0; q_ < 4; ++q_) {      \
        int n_ = q_ >> 1, ks2_ = q_ & 1;                                            \
        size_t off_ = ((((size_t)bh * 2 + n_) * 128 + (CH) * 2 + ks2_) * 64 + lane) * 8; \
        DST[q_] = *(const f16x8*)(vf + off_); } } while (0)

union SMemU {
    float combuf[2][32][64];   // 16 KB exchange buffer (softmax combine, ctx reduce)
    f16 sbuf[2][4][32][136];   // 68 KB double-buffered P stage: 272B rows
                               // (68w % 32 == 4, proven conflict-free b128 class)
};

__global__ __launch_bounds__(256, 2) void kattn(
    const f16* __restrict__ qfh, const f16* __restrict__ qfl,
    const f16* __restrict__ kfh, const f16* __restrict__ kfl,
    const f16* __restrict__ vf,
    float* __restrict__ ctx_out, float* __restrict__ attn_out) {
    __shared__ __align__(16) SMemU sm;
    int id = blockIdx.x;                              // 1024; 4 bh per XCD for K/V L2 locality
    int bh = (id & 7) * 4 + (id >> 8);
    int qt = (id >> 3) & 31;
    int wave = threadIdx.x >> 6, lane = threadIdx.x & 63;
    int qg = wave >> 1, kg = wave & 1;
    int lane31 = lane & 31, khalf = lane >> 5;
    int q0 = qt * 64 + qg * 32;

    // resident Q fragments (hi/lo): 4 ksteps of 16 over d_k=64, contiguous 1KB loads
    f16x8 a_h[4], a_l[4];
    {
        size_t qb = ((size_t)bh * 64 + qt * 2 + qg) * 4;
#pragma unroll
        for (int ks = 0; ks < 4; ++ks) {
            a_h[ks] = *(const f16x8*)(qfh + ((qb + ks) * 64 + lane) * 8);
            a_l[ks] = *(const f16x8*)(qfl + ((qb + ks) * 64 + lane) * 8);
        }
    }
    const f16* kbh = kfh + (size_t)bh * 131072;
    const f16* kbl = kfl + (size_t)bh * 131072;
    const int ch0 = kg * 32, ch1 = ch0 + 32;

    float m[16], s[16];
#pragma unroll
    for (int r = 0; r < 16; ++r) { m[r] = -3.0e38f; s[r] = 0.f; }

    // ---- pass 1: online row max + sum of 2^z, K register ping-pong ----
    {
        f16x8 KA[8], KB[8];
        LOADK(KA, ch0);
        for (int ch = ch0; ch < ch1; ch += 2) {
            LOADK(KB, ch + 1);
            f32x16 acc;
#pragma unroll
            for (int r = 0; r < 16; ++r) acc[r] = 0.f;
            QKM(KA, acc);
            SMUPD(acc);
            {
                int chn = (ch + 2 < ch1) ? ch + 2 : ch;
                LOADK(KA, chn);
            }
            f32x16 acc2;
#pragma unroll
            for (int r = 0; r < 16; ++r) acc2[r] = 0.f;
            QKM(KB, acc2);
            SMUPD(acc2);
        }
    }
    // lane combine within the 32 col-lanes of each half
#pragma unroll
    for (int r = 0; r < 16; ++r) {
        float mm = m[r], ss = s[r];
#pragma unroll
        for (int off = 1; off < 32; off <<= 1) {
            float mo = __shfl_xor(mm, off, 64);
            float so = __shfl_xor(ss, off, 64);
            float mn = fmaxf(mm, mo);
            ss = ss * exp2f(mm - mn) + so * exp2f(mo - mn);
            mm = mn;
        }
        m[r] = mm; s[r] = ss;
    }
    // cross-wave (k-split) combine through LDS
    if (kg == 1) {
#pragma unroll
        for (int r = 0; r < 16; ++r) {
            sm.combuf[qg][r][lane] = m[r];
            sm.combuf[qg][16 + r][lane] = s[r];
        }
    }
    __syncthreads();
    if (kg == 0) {
#pragma unroll
        for (int r = 0; r < 16; ++r) {
            float m1 = sm.combuf[qg][r][lane];
            float s1 = sm.combuf[qg][16 + r][lane];
            float mn = fmaxf(m[r], m1);
            float ss = s[r] * exp2f(m[r] - mn) + s1 * exp2f(m1 - mn);
            m[r] = mn; s[r] = 1.f / ss;
            sm.combuf[qg][r][lane] = mn;
            sm.combuf[qg][16 + r][lane] = s[r];
        }
    }
    __syncthreads();
    if (kg == 1) {
#pragma unroll
        for (int r = 0; r < 16; ++r) {
            m[r] = sm.combuf[qg][r][lane];
            s[r] = sm.combuf[qg][16 + r][lane];
        }
    }
    __syncthreads();   // union hazard: combuf reads must finish before sbuf writes

    f32x16 ctx[2];
#pragma unroll
    for (int n = 0; n < 2; ++n)
#pragma unroll
        for (int r = 0; r < 16; ++r) ctx[n][r] = 0.f;

    const size_t rowbase = ((size_t)bh * Ll + q0) * Ll;

    // ---- pass 2: recompute scores (identical op order); P staged in dbuf sbuf;
    //      sweep of buffer s-1 interleaved into superstep s (stores always
    //      younger than the loads compute waits on) ----
    {
        f16x8 KV[8], VV[4];
        LOADK(KV, ch0);
        LOADV(VV, ch0);
        int sst = 0;
        for (int chb = ch0; chb < ch1; chb += 4, sst ^= 1) {
#pragma unroll
            for (int i = 0; i < 4; ++i) {
                int ch = chb + i;
                f32x16 acc;
#pragma unroll
                for (int r = 0; r < 16; ++r) acc[r] = 0.f;
                QKM(KV, acc);
                int chn = (ch + 1 < ch1) ? ch + 1 : ch;
                LOADK(KV, chn);              // WAR on KV: safe after MFMA issue
#pragma unroll
                for (int r = 0; r < 16; ++r) {
                    float p = exp2f(acc[r] - m[r]) * s[r];
                    int row = (r & 3) + ((r >> 2) << 3) + (khalf << 2);
                    sm.sbuf[sst][wave][row][i * 32 + lane31] = (f16)p;
                }
                __asm__ volatile("s_waitcnt lgkmcnt(0)" ::: "memory");  // wave-private LDS RAW
#pragma unroll
                for (int ks2 = 0; ks2 < 2; ++ks2) {
                    f16x8 pa = *(const f16x8*)&sm.sbuf[sst][wave][lane31][i * 32 + ks2 * 16 + khalf * 8];
                    ctx[0] = MFMA32(pa, VV[ks2], ctx[0]);
                    ctx[1] = MFMA32(pa, VV[2 + ks2], ctx[1]);
                }
                LOADV(VV, chn);              // covered by next QK cluster
                // interleaved sweep: 4 rows of the PREVIOUS superstep's buffer,
                // issued after this ch's loads -> never older than a needed load
                if (chb > ch0) {
                    int chbp = chb - 4;
#pragma unroll
                    for (int q = 0; q < 4; ++q) {
                        int ri = i * 4 + q;
                        int row = ri * 2 + khalf;
                        f16x4 pv = *(const f16x4*)&sm.sbuf[sst ^ 1][wave][row][lane31 * 4];
                        f32x4 o = {(float)pv[0], (float)pv[1], (float)pv[2], (float)pv[3]};
                        *(f32x4*)(attn_out + rowbase + (size_t)row * Ll + chbp * 32 + lane31 * 4) = o;
                    }
                }
            }
        }
        // epilogue sweep: last superstep's buffer (sst toggled past it -> sst^1)
        {
            int chbp = ch1 - 4;
#pragma unroll
            for (int ri = 0; ri < 16; ++ri) {
                int row = ri * 2 + khalf;
                f16x4 pv = *(const f16x4*)&sm.sbuf[sst ^ 1][wave][row][lane31 * 4];
                f32x4 o = {(float)pv[0], (float)pv[1], (float)pv[2], (float)pv[3]};
                *(f32x4*)(attn_out + rowbase + (size_t)row * Ll + chbp * 32 + lane31 * 4) = o;
            }
        }
    }
    // ---- k-split ctx reduction ----
    __syncthreads();
    if (kg == 1) {
#pragma unroll
        for (int n = 0; n < 2; ++n)
#pragma unroll
            for (int r = 0; r < 16; ++r) sm.combuf[qg][n * 16 + r][lane] = ctx[n][r];
    }
    __syncthreads();
    if (kg == 0) {
#pragma unroll
        for (int n = 0; n < 2; ++n)
#pragma unroll
            for (int r = 0; r < 16; ++r) {
                float v = ctx[n][r] + sm.combuf[qg][n * 16 + r][lane];
                int row = (r & 3) + ((r >> 2) << 3) + (khalf << 2);
                ctx_out[((size_t)bh * Ll + q0 + row) * Dk + n * 32 + lane31] = v;
            }
    }
}

extern "C" void kernel_launch(void* const* d_in, const int* in_sizes, int n_in,
                              void* d_out, int out_size, void* d_ws, size_t ws_size,
                              hipStream_t stream) {
    const float* Q = (const float*)d_in[0];
    const float* K = (const float*)d_in[1];
    const float* V = (const float*)d_in[2];
    // d_in[3] = attn_mask (all-false, unused)
    const float* convq = (const float*)d_in[4];
    const float* convk = (const float*)d_in[5];
    const float* w = (const float*)d_in[6];

    char* ws = (char*)d_ws;
    int* flag = (int*)ws;
    f16* wfhq = (f16*)(ws + OFF_WF);
    f16* wflq = wfhq + NWF;
    f16* wfhk = wflq + NWF;
    f16* wflk = wfhk + NWF;
    f16* ffhq = (f16*)(ws + OFF_FF);
    f16* fflq = ffhq + NFF;
    f16* ffhk = fflq + NFF;
    f16* fflk = ffhk + NFF;
    f16* vf = (f16*)(ws + OFF_VF);

    float* ctx_out = (float*)d_out;
    float* attn_out = ctx_out + (size_t)BH * Ll * Dk;

    kprep_w<<<dim3(128, 2), 256, 0, stream>>>(convq, convk, w, flag, wfhq, wflq, wfhk, wflk);
    kprep_v<<<dim3(16, 32), 256, 0, stream>>>(V, vf);
    kconv<<<dim3(512), 512, 0, stream>>>(Q, K, flag,
                                         wfhq, wflq, wfhk, wflk, ffhq, fflq, ffhk, fflk);
    kattn<<<dim3(1024), 256, 0, stream>>>(ffhq, fflq, ffhk, fflk, vf, ctx_out, attn_out);
}

// Round 13
// 865.747 us; speedup vs baseline: 1.5637x; 1.0548x over previous
//
#include <hip/hip_runtime.h>

typedef _Float16 f16;
typedef _Float16 f16x4 __attribute__((ext_vector_type(4)));
typedef _Float16 f16x8 __attribute__((ext_vector_type(8)));
typedef float f32x4 __attribute__((ext_vector_type(4)));
typedef float f32x16 __attribute__((ext_vector_type(16)));

#define MFMA32(A, B, C) __builtin_amdgcn_mfma_f32_32x32x16_f16(A, B, C, 0, 0, 0)

constexpr int Bb = 4, Hh = 8, Ll = 2048, Dk = 64, Dm = 512, BH = 32;

// element counts per (tensor,hilo) array
constexpr size_t NWF = (size_t)16 * 128 * 64 * 8;      // W frag: [ob16][k16:128][lane][8]
constexpr size_t NFF = (size_t)BH * 64 * 4 * 64 * 8;   // Qc/Kc frag: [bh][lb64][d16:4][lane][8]
constexpr size_t NVF = (size_t)BH * 2 * 128 * 64 * 8;  // V frag: [bh][db2][l16:128][lane][8]

constexpr size_t OFF_WF = 256;
constexpr size_t OFF_FF = OFF_WF + 4 * NWF * sizeof(f16);
constexpr size_t OFF_VF = OFF_FF + 4 * NFF * sizeof(f16);

// scores computed in base-2: fold log2(e)/sqrt(64) into Qc (exact softmax identity)
#define QSCALE 0.1803368801111204f

// ---------------- P1: mask + split conv weights into frag order ----------------
__global__ void kprep_w(const float* __restrict__ convq, const float* __restrict__ convk,
                        const float* __restrict__ w, int* __restrict__ flag,
                        f16* __restrict__ wfhq, f16* __restrict__ wflq,
                        f16* __restrict__ wfhk, f16* __restrict__ wflk) {
    const int len = (4.f * w[1] > 2.f * w[0]) ? 4 : 2;   // argmax([2w0,4w1]) -> FILTER_LENGTHS[ind]
    if (blockIdx.x == 0 && blockIdx.y == 0 && threadIdx.x == 0) *flag = len;
    int g = blockIdx.x * 256 + threadIdx.x;              // [0,32768) = c8*512 + o
    int o = g & 511, c8 = g >> 9;                        // c = c8*8 + cc
    const float* conv = blockIdx.y ? convk : convq;
    f16* dh = blockIdx.y ? wfhk : wfhq;
    f16* dl = blockIdx.y ? wflk : wflq;
    float4 v[8];
#pragma unroll
    for (int cc = 0; cc < 8; ++cc)                       // coalesced: lanes read consecutive float4
        v[cc] = *(const float4*)(conv + ((size_t)(c8 * 8 + cc) * 512 + o) * 4);
    int ob = o >> 5;
#pragma unroll
    for (int f = 0; f < 4; ++f) {
        f16x8 hv, lv;
#pragma unroll
        for (int cc = 0; cc < 8; ++cc) {
            float x = (f < len) ? ((const float*)&v[cc])[f] : 0.f;
            f16 hi = (f16)x;
            hv[cc] = hi; lv[cc] = (f16)(x - (float)hi);
        }
        // k = f*512 + c8*8 + cc: k&7=cc, (k>>3)&1=c8&1, k16=f*32+(c8>>1)
        int k16 = f * 32 + (c8 >> 1);
        size_t base = (((size_t)ob * 128 + k16) * 64 + (c8 & 1) * 32 + (o & 31)) * 8;
        *(f16x8*)(dh + base) = hv;
        *(f16x8*)(dl + base) = lv;
    }
}

// ---------------- P3: V -> frag order for PV B-operand ----------------
__global__ void kprep_v(const float* __restrict__ V, f16* __restrict__ vf) {
    int bh = blockIdx.y, l0 = blockIdx.x * 128;
    int tid = threadIdx.x;
    const float* src = V + (size_t)bh * Ll * Dk;
#pragma unroll
    for (int s = 0; s < 4; ++s) {
        int g = s * 4 + (tid >> 6);
        int lane = tid & 63;
        int l16s = g >> 1, db = g & 1;
        int khalf = lane >> 5, lane31 = lane & 31;
        int d = db * 32 + lane31;
        f16x8 out;
#pragma unroll
        for (int j = 0; j < 8; ++j) {
            int l = l0 + l16s * 16 + khalf * 8 + j;
            out[j] = (f16)src[(size_t)l * Dk + d];
        }
        size_t idx = ((((size_t)bh * 2 + db) * 128 + (l0 >> 4) + l16s) * 64 + lane) * 8;
        *(f16x8*)(vf + idx) = out;
    }
}

// ---------------- C: conv GEMM, 512-thread blocks (8 waves = 4 wm x 2 wn) ----------------
// (unchanged from R12)
__global__ __launch_bounds__(512, 2) void kconv(
    const float* __restrict__ Q, const float* __restrict__ K, const int* __restrict__ flag,
    const f16* __restrict__ wfhq, const f16* __restrict__ wflq,
    const f16* __restrict__ wfhk, const f16* __restrict__ wflk,
    f16* __restrict__ ffhq, f16* __restrict__ fflq,
    f16* __restrict__ ffhk, f16* __restrict__ fflk) {
    __shared__ __align__(16) f16 est[8][2][32][40];   // 40 KB
    int id = blockIdx.x;
    int xcd = id & 7, oB = (id >> 3) & 3, gidx = id >> 5;     // gidx in [0,16)
    int g = gidx * 8 + xcd;                                   // [0,128)
    int ttB = g & 15, b = (g >> 4) & 3, tensor = (g >> 6) & 1;
    int wave = threadIdx.x >> 6, lane = threadIdx.x & 63;     // wave in [0,8)
    int wn = wave & 1, wm = wave >> 1;                        // wm in [0,4)
    int lane31 = lane & 31, khalf = lane >> 5;
    const f16* bhp = (tensor ? wfhk : wfhq) + ((size_t)(oB * 4 + wn * 2) * 128) * 512;
    const f16* blp = (tensor ? wflk : wflq) + ((size_t)(oB * 4 + wn * 2) * 128) * 512;
    const float* src = (tensor ? K : Q) + (size_t)b * Dm * Ll;  // flat [512][2048] view
    f16* dh = (tensor ? ffhk : ffhq);
    f16* dl = (tensor ? fflk : fflq);
    const float scale = tensor ? 1.f : QSCALE;
    const int klen16 = (*flag) << 5;            // 128 or 64 (even)
    const int t0 = (ttB * 4 + wm) * 32;
    const int coff = khalf * 8;

    f32x16 acc[2];
#pragma unroll
    for (int j = 0; j < 2; ++j)
#pragma unroll
        for (int r = 0; r < 16; ++r) acc[j][r] = 0.f;

    f16x8 Abh[2], Abl[2], Bbh[2], Bbl[2];       // W ping-pong buffers
    float XA[8], XB[8], mkA, mkB;               // A-source octet ping-pong (f32)
    const size_t lo8 = (size_t)lane * 8;

#define LOADX(X, MK, KN) do {                                                        \
    int f_ = (KN) >> 5;                                                              \
    int cb_ = (((KN) >> 2) & 7) * 64 + ((KN) & 3) * 16 + coff;                       \
    int t_ = t0 - 2 + lane31 + f_;                                                   \
    int tc_ = t_ < 0 ? 0 : (t_ > Ll - 1 ? Ll - 1 : t_);                              \
    MK = (t_ == tc_) ? 1.f : 0.f;                                                    \
    const float* sp_ = src + (size_t)cb_ * Ll + tc_;                                 \
    _Pragma("unroll") for (int j_ = 0; j_ < 8; ++j_) X[j_] = sp_[(size_t)j_ * Ll];   \
} while (0)

#define CVTA(X, MK, AH, AL) do {                                                     \
    _Pragma("unroll") for (int j_ = 0; j_ < 8; ++j_) {                               \
        float x_ = X[j_] * MK; f16 h_ = (f16)x_;                                     \
        AH[j_] = h_; AL[j_] = (f16)(x_ - (float)h_); }                               \
} while (0)

    // prime buffer A with k16=0
    LOADX(XA, mkA, 0);
    Abh[0] = *(const f16x8*)(bhp + lo8);
    Abl[0] = *(const f16x8*)(blp + lo8);
    Abh[1] = *(const f16x8*)(bhp + 128 * 512 + lo8);
    Abl[1] = *(const f16x8*)(blp + 128 * 512 + lo8);

    for (int k16 = 0; k16 < klen16; k16 += 2) {
        {   // prefetch k16+1 into B
            int kn = k16 + 1;
            LOADX(XB, mkB, kn);
            size_t o = (size_t)kn * 512 + lo8;
            Bbh[0] = *(const f16x8*)(bhp + o);
            Bbl[0] = *(const f16x8*)(blp + o);
            Bbh[1] = *(const f16x8*)(bhp + 128 * 512 + o);
            Bbl[1] = *(const f16x8*)(blp + 128 * 512 + o);
        }
        {
            f16x8 Ah, Al;
            CVTA(XA, mkA, Ah, Al);
#pragma unroll
            for (int j = 0; j < 2; ++j) {
                acc[j] = MFMA32(Ah, Abh[j], acc[j]);
                acc[j] = MFMA32(Ah, Abl[j], acc[j]);
                acc[j] = MFMA32(Al, Abh[j], acc[j]);
            }
        }
        {   // prefetch k16+2 into A
            int kn = k16 + 2 < klen16 ? k16 + 2 : klen16 - 1;
            LOADX(XA, mkA, kn);
            size_t o = (size_t)kn * 512 + lo8;
            Abh[0] = *(const f16x8*)(bhp + o);
            Abl[0] = *(const f16x8*)(blp + o);
            Abh[1] = *(const f16x8*)(bhp + 128 * 512 + o);
            Abl[1] = *(const f16x8*)(blp + 128 * 512 + o);
        }
        {
            f16x8 Bh, Bl;
            CVTA(XB, mkB, Bh, Bl);
#pragma unroll
            for (int j = 0; j < 2; ++j) {
                acc[j] = MFMA32(Bh, Bbh[j], acc[j]);
                acc[j] = MFMA32(Bh, Bbl[j], acc[j]);
                acc[j] = MFMA32(Bl, Bbh[j], acc[j]);
            }
        }
    }
#undef LOADX
#undef CVTA
    // epilogue: stage wave's 32x64 C tile (hi/lo) in LDS, write f16x8 chunks.
    const int lcol = oB * 2 + wn;               // ocol>>6, constant per wave
#pragma unroll
    for (int j = 0; j < 2; ++j) {
#pragma unroll
        for (int r = 0; r < 16; ++r) {
            int tl = (r & 3) + ((r >> 2) << 3) + (khalf << 2);   // 0..31
            int trow = ttB * 128 + wm * 32 + tl;
            int h = trow >> 8;
            int l = ((trow & 255) << 3) + lcol;
            int d = j * 32 + lane31;
            float v2 = (acc[j][r] + src[((size_t)h * Ll + l) * Dk + d]) * scale;
            f16 hi = (f16)v2;
            est[wave][0][tl][lane31] = hi;
            est[wave][1][tl][lane31] = (f16)(v2 - (float)hi);
        }
        __asm__ volatile("s_waitcnt lgkmcnt(0)" ::: "memory");   // wave-private LDS RAW
#pragma unroll
        for (int c = 0; c < 2; ++c) {
            int id2 = c * 64 + lane;            // 0..127
            int row = id2 >> 2;                 // t_local 0..31
            int dc = id2 & 3;                   // 8-col chunk within j's 32 cols
            int trow = ttB * 128 + wm * 32 + row;
            int h = trow >> 8;
            int l = ((trow & 255) << 3) + lcol;
            size_t base2 = ((size_t)(b * 8 + h) * 64 + (l >> 5)) * 4;
            size_t idx = (base2 + j * 2 + (dc >> 1)) * 512 + (size_t)(dc & 1) * 256 + (l & 31) * 8;
            f16x8 hv = *(const f16x8*)&est[wave][0][row][dc * 8];
            f16x8 lv = *(const f16x8*)&est[wave][1][row][dc * 8];
            *(f16x8*)(dh + idx) = hv;
            *(f16x8*)(dl + idx) = lv;
        }
        __asm__ volatile("s_waitcnt lgkmcnt(0)" ::: "memory");   // reads done before next j WAR
    }
}

// ---------------- F: fused attention, K-split across wave pairs ----------------
// R13 == R11/R12 structure + NONTEMPORAL sweep stores. R3's "nt poisons caches"
// was confounded: R3 ran 3 blk/CU (pre-union 50.8KB LDS), and R7 showed 3 blk/CU
// alone causes the FETCH blowup (201MB, cached stores). At 3 blk, nt (437us) was
// actually FASTER than cached (457us). nt at the proven 2 blk/CU routes the
// write-once attn stream around L2 dirty-eviction (the residual drain limiter)
// while K/V keep their healthy cache behavior (FETCH 78MB).
#define LOADK(DST, CH) do { size_t kb_ = (size_t)(CH) * 2048 + lane * 8;            \
    _Pragma("unroll") for (int ks_ = 0; ks_ < 4; ++ks_) {                           \
        DST[2 * ks_]     = *(const f16x8*)(kbh + kb_ + ks_ * 512);                  \
        DST[2 * ks_ + 1] = *(const f16x8*)(kbl + kb_ + ks_ * 512); } } while (0)

#define QKM(SRC, ACC) do { _Pragma("unroll") for (int ks_ = 0; ks_ < 4; ++ks_) {    \
        ACC = MFMA32(a_h[ks_], SRC[2 * ks_], ACC);                                  \
        ACC = MFMA32(a_h[ks_], SRC[2 * ks_ + 1], ACC);                              \
        ACC = MFMA32(a_l[ks_], SRC[2 * ks_], ACC); } } while (0)

#define SMUPD(ACC) do { _Pragma("unroll") for (int r_ = 0; r_ < 16; ++r_) {         \
        float v_ = ACC[r_]; float d_ = v_ - m[r_]; float e_ = exp2f(-fabsf(d_));    \
        bool gt_ = d_ > 0.f;                                                        \
        s[r_] = gt_ ? __fmaf_rn(s[r_], e_, 1.f) : (s[r_] + e_);                     \
        m[r_] = gt_ ? v_ : m[r_]; } } while (0)

#define LOADV(DST, CH) do { _Pragma("unroll") for (int q_ = 0; q_ < 4; ++q_) {      \
        int n_ = q_ >> 1, ks2_ = q_ & 1;                                            \
        size_t off_ = ((((size_t)bh * 2 + n_) * 128 + (CH) * 2 + ks2_) * 64 + lane) * 8; \
        DST[q_] = *(const f16x8*)(vf + off_); } } while (0)

union SMemU {
    float combuf[2][32][64];   // 16 KB exchange buffer (softmax combine, ctx reduce)
    f16 sbuf[2][4][32][136];   // 68 KB double-buffered P stage: 272B rows
                               // (68w % 32 == 4, proven conflict-free b128 class)
};

__global__ __launch_bounds__(256, 2) void kattn(
    const f16* __restrict__ qfh, const f16* __restrict__ qfl,
    const f16* __restrict__ kfh, const f16* __restrict__ kfl,
    const f16* __restrict__ vf,
    float* __restrict__ ctx_out, float* __restrict__ attn_out) {
    __shared__ __align__(16) SMemU sm;
    int id = blockIdx.x;                              // 1024; 4 bh per XCD for K/V L2 locality
    int bh = (id & 7) * 4 + (id >> 8);
    int qt = (id >> 3) & 31;
    int wave = threadIdx.x >> 6, lane = threadIdx.x & 63;
    int qg = wave >> 1, kg = wave & 1;
    int lane31 = lane & 31, khalf = lane >> 5;
    int q0 = qt * 64 + qg * 32;

    // resident Q fragments (hi/lo): 4 ksteps of 16 over d_k=64, contiguous 1KB loads
    f16x8 a_h[4], a_l[4];
    {
        size_t qb = ((size_t)bh * 64 + qt * 2 + qg) * 4;
#pragma unroll
        for (int ks = 0; ks < 4; ++ks) {
            a_h[ks] = *(const f16x8*)(qfh + ((qb + ks) * 64 + lane) * 8);
            a_l[ks] = *(const f16x8*)(qfl + ((qb + ks) * 64 + lane) * 8);
        }
    }
    const f16* kbh = kfh + (size_t)bh * 131072;
    const f16* kbl = kfl + (size_t)bh * 131072;
    const int ch0 = kg * 32, ch1 = ch0 + 32;

    float m[16], s[16];
#pragma unroll
    for (int r = 0; r < 16; ++r) { m[r] = -3.0e38f; s[r] = 0.f; }

    // ---- pass 1: online row max + sum of 2^z, K register ping-pong ----
    {
        f16x8 KA[8], KB[8];
        LOADK(KA, ch0);
        for (int ch = ch0; ch < ch1; ch += 2) {
            LOADK(KB, ch + 1);
            f32x16 acc;
#pragma unroll
            for (int r = 0; r < 16; ++r) acc[r] = 0.f;
            QKM(KA, acc);
            SMUPD(acc);
            {
                int chn = (ch + 2 < ch1) ? ch + 2 : ch;
                LOADK(KA, chn);
            }
            f32x16 acc2;
#pragma unroll
            for (int r = 0; r < 16; ++r) acc2[r] = 0.f;
            QKM(KB, acc2);
            SMUPD(acc2);
        }
    }
    // lane combine within the 32 col-lanes of each half
#pragma unroll
    for (int r = 0; r < 16; ++r) {
        float mm = m[r], ss = s[r];
#pragma unroll
        for (int off = 1; off < 32; off <<= 1) {
            float mo = __shfl_xor(mm, off, 64);
            float so = __shfl_xor(ss, off, 64);
            float mn = fmaxf(mm, mo);
            ss = ss * exp2f(mm - mn) + so * exp2f(mo - mn);
            mm = mn;
        }
        m[r] = mm; s[r] = ss;
    }
    // cross-wave (k-split) combine through LDS
    if (kg == 1) {
#pragma unroll
        for (int r = 0; r < 16; ++r) {
            sm.combuf[qg][r][lane] = m[r];
            sm.combuf[qg][16 + r][lane] = s[r];
        }
    }
    __syncthreads();
    if (kg == 0) {
#pragma unroll
        for (int r = 0; r < 16; ++r) {
            float m1 = sm.combuf[qg][r][lane];
            float s1 = sm.combuf[qg][16 + r][lane];
            float mn = fmaxf(m[r], m1);
            float ss = s[r] * exp2f(m[r] - mn) + s1 * exp2f(m1 - mn);
            m[r] = mn; s[r] = 1.f / ss;
            sm.combuf[qg][r][lane] = mn;
            sm.combuf[qg][16 + r][lane] = s[r];
        }
    }
    __syncthreads();
    if (kg == 1) {
#pragma unroll
        for (int r = 0; r < 16; ++r) {
            m[r] = sm.combuf[qg][r][lane];
            s[r] = sm.combuf[qg][16 + r][lane];
        }
    }
    __syncthreads();   // union hazard: combuf reads must finish before sbuf writes

    f32x16 ctx[2];
#pragma unroll
    for (int n = 0; n < 2; ++n)
#pragma unroll
        for (int r = 0; r < 16; ++r) ctx[n][r] = 0.f;

    const size_t rowbase = ((size_t)bh * Ll + q0) * Ll;

    // ---- pass 2: recompute scores (identical op order); P staged in dbuf sbuf;
    //      sweep of buffer s-1 interleaved into superstep s (stores always
    //      younger than the loads compute waits on), NONTEMPORAL ----
    {
        f16x8 KV[8], VV[4];
        LOADK(KV, ch0);
        LOADV(VV, ch0);
        int sst = 0;
        for (int chb = ch0; chb < ch1; chb += 4, sst ^= 1) {
#pragma unroll
            for (int i = 0; i < 4; ++i) {
                int ch = chb + i;
                f32x16 acc;
#pragma unroll
                for (int r = 0; r < 16; ++r) acc[r] = 0.f;
                QKM(KV, acc);
                int chn = (ch + 1 < ch1) ? ch + 1 : ch;
                LOADK(KV, chn);              // WAR on KV: safe after MFMA issue
#pragma unroll
                for (int r = 0; r < 16; ++r) {
                    float p = exp2f(acc[r] - m[r]) * s[r];
                    int row = (r & 3) + ((r >> 2) << 3) + (khalf << 2);
                    sm.sbuf[sst][wave][row][i * 32 + lane31] = (f16)p;
                }
                __asm__ volatile("s_waitcnt lgkmcnt(0)" ::: "memory");  // wave-private LDS RAW
#pragma unroll
                for (int ks2 = 0; ks2 < 2; ++ks2) {
                    f16x8 pa = *(const f16x8*)&sm.sbuf[sst][wave][lane31][i * 32 + ks2 * 16 + khalf * 8];
                    ctx[0] = MFMA32(pa, VV[ks2], ctx[0]);
                    ctx[1] = MFMA32(pa, VV[2 + ks2], ctx[1]);
                }
                LOADV(VV, chn);              // covered by next QK cluster
                // interleaved sweep: 4 rows of the PREVIOUS superstep's buffer,
                // issued after this ch's loads -> never older than a needed load
                if (chb > ch0) {
                    int chbp = chb - 4;
#pragma unroll
                    for (int q = 0; q < 4; ++q) {
                        int ri = i * 4 + q;
                        int row = ri * 2 + khalf;
                        f16x4 pv = *(const f16x4*)&sm.sbuf[sst ^ 1][wave][row][lane31 * 4];
                        f32x4 o = {(float)pv[0], (float)pv[1], (float)pv[2], (float)pv[3]};
                        __builtin_nontemporal_store(
                            o, (f32x4*)(attn_out + rowbase + (size_t)row * Ll + chbp * 32 + lane31 * 4));
                    }
                }
            }
        }
        // epilogue sweep: last superstep's buffer (sst toggled past it -> sst^1)
        {
            int chbp = ch1 - 4;
#pragma unroll
            for (int ri = 0; ri < 16; ++ri) {
                int row = ri * 2 + khalf;
                f16x4 pv = *(const f16x4*)&sm.sbuf[sst ^ 1][wave][row][lane31 * 4];
                f32x4 o = {(float)pv[0], (float)pv[1], (float)pv[2], (float)pv[3]};
                __builtin_nontemporal_store(
                    o, (f32x4*)(attn_out + rowbase + (size_t)row * Ll + chbp * 32 + lane31 * 4));
            }
        }
    }
    // ---- k-split ctx reduction ----
    __syncthreads();
    if (kg == 1) {
#pragma unroll
        for (int n = 0; n < 2; ++n)
#pragma unroll
            for (int r = 0; r < 16; ++r) sm.combuf[qg][n * 16 + r][lane] = ctx[n][r];
    }
    __syncthreads();
    if (kg == 0) {
#pragma unroll
        for (int n = 0; n < 2; ++n)
#pragma unroll
            for (int r = 0; r < 16; ++r) {
                float v = ctx[n][r] + sm.combuf[qg][n * 16 + r][lane];
                int row = (r & 3) + ((r >> 2) << 3) + (khalf << 2);
                ctx_out[((size_t)bh * Ll + q0 + row) * Dk + n * 32 + lane31] = v;
            }
    }
}

extern "C" void kernel_launch(void* const* d_in, const int* in_sizes, int n_in,
                              void* d_out, int out_size, void* d_ws, size_t ws_size,
                              hipStream_t stream) {
    const float* Q = (const float*)d_in[0];
    const float* K = (const float*)d_in[1];
    const float* V = (const float*)d_in[2];
    // d_in[3] = attn_mask (all-false, unused)
    const float* convq = (const float*)d_in[4];
    const float* convk = (const float*)d_in[5];
    const float* w = (const float*)d_in[6];

    char* ws = (char*)d_ws;
    int* flag = (int*)ws;
    f16* wfhq = (f16*)(ws + OFF_WF);
    f16* wflq = wfhq + NWF;
    f16* wfhk = wflq + NWF;
    f16* wflk = wfhk + NWF;
    f16* ffhq = (f16*)(ws + OFF_FF);
    f16* fflq = ffhq + NFF;
    f16* ffhk = fflq + NFF;
    f16* fflk = ffhk + NFF;
    f16* vf = (f16*)(ws + OFF_VF);

    float* ctx_out = (float*)d_out;
    float* attn_out = ctx_out + (size_t)BH * Ll * Dk;

    kprep_w<<<dim3(128, 2), 256, 0, stream>>>(convq, convk, w, flag, wfhq, wflq, wfhk, wflk);
    kprep_v<<<dim3(16, 32), 256, 0, stream>>>(V, vf);
    kconv<<<dim3(512), 512, 0, stream>>>(Q, K, flag,
                                         wfhq, wflq, wfhk, wflk, ffhq, fflq, ffhk, fflk);
    kattn<<<dim3(1024), 256, 0, stream>>>(ffhq, fflq, ffhk, fflk, vf, ctx_out, attn_out);
}